// Round 1
// baseline (1210.502 us; speedup 1.0000x reference)
//
#include <hip/hip_runtime.h>
#include <stdint.h>

#define B_ 4
#define T_ 4096
#define D_ 1024
#define H_ 16
#define NPAD 2176            // 1024 k + 1024 v + 16 beta + 16 g + 96 zero-pad (multiple of 128)
#define ROWS (B_*T_)         // 16384

typedef __bf16 bf16x8 __attribute__((ext_vector_type(8)));
typedef float  f32x4  __attribute__((ext_vector_type(4)));
typedef unsigned short u16;
typedef u16 u16x8 __attribute__((ext_vector_type(8)));
typedef u16 u16x4 __attribute__((ext_vector_type(4)));

__device__ __forceinline__ float bf2f(u16 u){
  union { unsigned int i; float f; } x; x.i = ((unsigned int)u) << 16; return x.f;
}
__device__ __forceinline__ u16 f2bf(float f){
  union { float f; unsigned int i; } x; x.f = f;
  unsigned int r = x.i + 0x7fffu + ((x.i >> 16) & 1u);
  return (u16)(r >> 16);
}

__device__ __forceinline__ void gload_lds16(const u16* g, u16* l){
  __builtin_amdgcn_global_load_lds(
      (const __attribute__((address_space(1))) unsigned int*)g,
      (__attribute__((address_space(3))) unsigned int*)l, 16, 0, 0);
}

// ---------------- weight prep: f32 -> bf16, pack [Wk;Wv;Wb;Wg;pad] ----------------
__global__ __launch_bounds__(256) void prep_w(
    const float* __restrict__ Wk, const float* __restrict__ Wv,
    const float* __restrict__ Wb, const float* __restrict__ Wg,
    const float* __restrict__ Wo, u16* __restrict__ Wcomb, u16* __restrict__ Wob)
{
  long i = (long)blockIdx.x * 256 + threadIdx.x;
  const long tot1 = (long)NPAD * D_;
  if (i < tot1) {
    long n = i >> 10, d = i & 1023;
    float v;
    if      (n < 1024) v = Wk[n * 1024 + d];
    else if (n < 2048) v = Wv[(n - 1024) * 1024 + d];
    else if (n < 2064) v = Wb[(n - 2048) * 1024 + d];
    else if (n < 2080) v = Wg[(n - 2064) * 1024 + d];
    else               v = 0.f;
    Wcomb[i] = f2bf(v);
  } else {
    long j = i - tot1;           // grid sized exactly: j < D_*D_
    Wob[j] = f2bf(Wo[j]);
  }
}

// ---------------- RMSNorm: x f32 -> xn bf16 ----------------
__global__ __launch_bounds__(256) void rmsnorm_k(
    const float* __restrict__ x, const float* __restrict__ w, u16* __restrict__ xn)
{
  long row = blockIdx.x;
  int tid = threadIdx.x;
  int l = tid & 63, wv = tid >> 6;
  f32x4 v = ((const f32x4*)(x + row * D_))[tid];
  float ss = v[0]*v[0] + v[1]*v[1] + v[2]*v[2] + v[3]*v[3];
  #pragma unroll
  for (int m = 1; m < 64; m <<= 1) ss += __shfl_xor(ss, m, 64);
  __shared__ float red[4];
  if (l == 0) red[wv] = ss;
  __syncthreads();
  float tot = red[0] + red[1] + red[2] + red[3];
  float inv = rsqrtf(tot * (1.f / (float)D_) + 1e-6f);
  f32x4 wv4 = ((const f32x4*)w)[tid];
  u16x4 o;
  o[0] = f2bf(v[0] * inv * wv4[0]);
  o[1] = f2bf(v[1] * inv * wv4[1]);
  o[2] = f2bf(v[2] * inv * wv4[2]);
  o[3] = f2bf(v[3] * inv * wv4[3]);
  ((u16x4*)(xn + row * D_))[tid] = o;
}

// ---------------- bf16 NT GEMM: C[M,N] = A[M,K] * B[N,K]^T ----------------
// 128x128 tile, BK=32, 4 waves (2x2), 16x16x32 MFMA, global_load_lds width-16 staging.
template<int RESID, int OUTF32>
__global__ __launch_bounds__(256) void gemm_nt(
    const u16* __restrict__ A, const u16* __restrict__ Bm,
    u16* __restrict__ Cb, float* __restrict__ Cf, const float* __restrict__ resid,
    int M, int N, int Kd)
{
  __shared__ __align__(16) u16 Als[128 * 32];
  __shared__ __align__(16) u16 Bls[128 * 32];
  const int tid = threadIdx.x;
  const int w = tid >> 6, l = tid & 63;
  const int wr = w >> 1, wc = w & 1;
  const int lm = l & 15, lq = l >> 4;
  const long bm0 = (long)blockIdx.y * 128;
  const long bn0 = (long)blockIdx.x * 128;

  f32x4 zero4 = {0.f, 0.f, 0.f, 0.f};
  f32x4 acc[4][4];
  #pragma unroll
  for (int i = 0; i < 4; i++)
    #pragma unroll
    for (int j = 0; j < 4; j++) acc[i][j] = zero4;

  for (int kk = 0; kk < Kd; kk += 32) {
    __syncthreads();
    #pragma unroll
    for (int it = 0; it < 2; it++) {
      int c = tid + it * 256;          // 0..511 chunk id (16B chunks)
      int r = c >> 2, kb = c & 3;      // row in tile, 8-elem group in BK
      const u16* ga = A  + (bm0 + r) * Kd + kk + kb * 8;
      const u16* gb = Bm + (bn0 + r) * Kd + kk + kb * 8;
      gload_lds16(ga, Als + (it * 256 + w * 64) * 8);
      gload_lds16(gb, Bls + (it * 256 + w * 64) * 8);
    }
    __syncthreads();
    bf16x8 af[4], bf[4];
    #pragma unroll
    for (int f = 0; f < 4; f++)
      af[f] = *(const bf16x8*)(Als + (wr * 64 + f * 16 + lm) * 32 + lq * 8);
    #pragma unroll
    for (int f = 0; f < 4; f++)
      bf[f] = *(const bf16x8*)(Bls + (wc * 64 + f * 16 + lm) * 32 + lq * 8);
    #pragma unroll
    for (int i = 0; i < 4; i++)
      #pragma unroll
      for (int j = 0; j < 4; j++)
        acc[i][j] = __builtin_amdgcn_mfma_f32_16x16x32_bf16(af[i], bf[j], acc[i][j], 0, 0, 0);
  }

  // epilogue: C/D layout col=lane&15, row=(lane>>4)*4+reg
  #pragma unroll
  for (int i = 0; i < 4; i++) {
    #pragma unroll
    for (int r = 0; r < 4; r++) {
      long m = bm0 + wr * 64 + i * 16 + lq * 4 + r;
      #pragma unroll
      for (int j = 0; j < 4; j++) {
        long n = bn0 + wc * 64 + j * 16 + lm;
        float val = acc[i][j][r];
        if (RESID) val += resid[m * N + n];
        if (OUTF32) Cf[m * N + n] = val;
        else        Cb[m * N + n] = f2bf(val);
      }
    }
  }
}

// ---------------- postprocess: L2-normalize k (in place), sigmoid beta/g -> [B,H,T] f32 ----------------
__global__ __launch_bounds__(64) void postproc(
    u16* __restrict__ kv, const float* __restrict__ bb, const float* __restrict__ bg,
    float* __restrict__ bArr, float* __restrict__ gArr)
{
  long row = blockIdx.x;             // 0..16383
  int l = threadIdx.x;
  u16* rp = kv + row * NPAD;
  #pragma unroll
  for (int h = 0; h < 16; h++) {
    float xk = bf2f(rp[h * 64 + l]);
    float ss = xk * xk;
    #pragma unroll
    for (int m = 1; m < 64; m <<= 1) ss += __shfl_xor(ss, m, 64);
    float inv = 1.f / fmaxf(sqrtf(ss), 1e-12f);
    rp[h * 64 + l] = f2bf(xk * inv);
  }
  if (l < 32) {
    int hh = l & 15;
    float val = bf2f(rp[2048 + l]) + ((l < 16) ? bb[hh] : bg[hh]);
    float s = 1.f / (1.f + expf(-val));
    float* dst = (l < 16) ? bArr : gArr;
    long b = row >> 12;              // T = 4096
    long t = row & 4095;
    dst[(b * H_ + hh) * (long)T_ + t] = s;
  }
}

// ---------------- gated delta-rule scan ----------------
// 64 blocks (b,h) x 256 threads (4 waves). Wave w owns v-columns w*16..w*16+15;
// lane = q*16+c: column c, k-slice q*16..q*16+15. Scaled state s~ = S/G.
// out = g*pred + beta*err  (uses ||k||=1).
__global__ __launch_bounds__(256) void scan_k(
    const u16* __restrict__ kv, const float* __restrict__ bArr,
    const float* __restrict__ gArr, u16* __restrict__ outArr)
{
  __shared__ __align__(16) float kls[64][64];   // [t][k]
  __shared__ __align__(16) float vls[64][64];   // [t][v]
  __shared__ float bls[64], gls[64];
  const int bh = blockIdx.x, b = bh >> 4, h = bh & 15;
  const int tid = threadIdx.x, w = tid >> 6, l = tid & 63;
  const int c = l & 15, q = l >> 4;
  const int vcol = w * 16 + c;
  const u16* kbase = kv + (long)b * T_ * NPAD + h * 64;
  const u16* vbase = kbase + 1024;
  const float* bp = bArr + (long)(b * H_ + h) * T_;
  const float* gp = gArr + (long)(b * H_ + h) * T_;
  u16* obase = outArr + (long)b * T_ * (long)D_ + h * 64;

  float st[16];
  #pragma unroll
  for (int j = 0; j < 16; j++) st[j] = 0.f;
  float G = 1.f;

  for (int ch = 0; ch < T_ / 64; ch++) {
    __syncthreads();
    // stage k,v chunk (bf16 -> f32) : 64 rows x 64 cols each
    #pragma unroll
    for (int i = 0; i < 2; i++) {
      int cc = tid * 2 + i;          // 0..511
      int r = cc >> 3, ko = (cc & 7) << 3;
      long off = (long)(ch * 64 + r) * NPAD + ko;
      u16x8 kvv = *(const u16x8*)(kbase + off);
      u16x8 vvv = *(const u16x8*)(vbase + off);
      f32x4 a0 = {bf2f(kvv[0]), bf2f(kvv[1]), bf2f(kvv[2]), bf2f(kvv[3])};
      f32x4 a1 = {bf2f(kvv[4]), bf2f(kvv[5]), bf2f(kvv[6]), bf2f(kvv[7])};
      f32x4 b0 = {bf2f(vvv[0]), bf2f(vvv[1]), bf2f(vvv[2]), bf2f(vvv[3])};
      f32x4 b1 = {bf2f(vvv[4]), bf2f(vvv[5]), bf2f(vvv[6]), bf2f(vvv[7])};
      *(f32x4*)&kls[r][ko]     = a0;
      *(f32x4*)&kls[r][ko + 4] = a1;
      *(f32x4*)&vls[r][ko]     = b0;
      *(f32x4*)&vls[r][ko + 4] = b1;
    }
    if (tid < 64)       bls[tid] = bp[ch * 64 + tid];
    else if (tid < 128) gls[tid - 64] = gp[ch * 64 + tid - 64];
    __syncthreads();

    #pragma unroll 16
    for (int t = 0; t < 64; t++) {
      const f32x4* kp = (const f32x4*)&kls[t][q * 16];
      float kq[16];
      *(f32x4*)&kq[0]  = kp[0];
      *(f32x4*)&kq[4]  = kp[1];
      *(f32x4*)&kq[8]  = kp[2];
      *(f32x4*)&kq[12] = kp[3];
      float vv = vls[t][vcol];
      float bt = bls[t], gt = gls[t];
      float p0 = 0.f, p1 = 0.f, p2 = 0.f, p3 = 0.f;
      #pragma unroll
      for (int j = 0; j < 4; j++) {
        p0 = fmaf(st[4*j+0], kq[4*j+0], p0);
        p1 = fmaf(st[4*j+1], kq[4*j+1], p1);
        p2 = fmaf(st[4*j+2], kq[4*j+2], p2);
        p3 = fmaf(st[4*j+3], kq[4*j+3], p3);
      }
      float p = (p0 + p1) + (p2 + p3);
      p += __shfl_xor(p, 16, 64);
      p += __shfl_xor(p, 32, 64);
      float Gp = G;
      G = G * gt;
      float pred = Gp * p;
      float err = vv - pred;
      float outv = fmaf(gt, pred, bt * err);
      float ccoef = (bt * err) * __builtin_amdgcn_rcpf(G);
      #pragma unroll
      for (int j = 0; j < 16; j++) st[j] = fmaf(ccoef, kq[j], st[j]);
      if (q == 0) obase[(long)(ch * 64 + t) * D_ + vcol] = f2bf(outv);
      if ((t & 15) == 15) {
        #pragma unroll
        for (int j = 0; j < 16; j++) st[j] *= G;
        G = 1.f;
      }
    }
  }
}

extern "C" void kernel_launch(void* const* d_in, const int* in_sizes, int n_in,
                              void* d_out, int out_size, void* d_ws, size_t ws_size,
                              hipStream_t stream) {
  const float* x     = (const float*)d_in[0];
  const float* normw = (const float*)d_in[1];
  const float* Wk    = (const float*)d_in[2];
  const float* Wv    = (const float*)d_in[3];
  const float* Wo    = (const float*)d_in[4];
  const float* Wb    = (const float*)d_in[5];
  const float* bb    = (const float*)d_in[6];
  const float* Wg    = (const float*)d_in[7];
  const float* bg    = (const float*)d_in[8];
  float* y = (float*)d_out;

  char* ws = (char*)d_ws;
  u16* xn    = (u16*)ws;   ws += (long)ROWS * D_ * 2;      // 33.5 MB
  u16* Wcomb = (u16*)ws;   ws += (long)NPAD * D_ * 2;      // 4.5 MB
  u16* Wob   = (u16*)ws;   ws += (long)D_ * D_ * 2;        // 2 MB
  u16* kvb   = (u16*)ws;   ws += (long)ROWS * NPAD * 2;    // 71.3 MB
  float* bA  = (float*)ws; ws += (long)B_ * H_ * T_ * 4;   // 1 MB
  float* gA  = (float*)ws; ws += (long)B_ * H_ * T_ * 4;   // 1 MB
  u16* outb  = (u16*)ws;   ws += (long)ROWS * D_ * 2;      // 33.5 MB

  const long prep_total = (long)NPAD * D_ + (long)D_ * D_;   // 3,276,800
  prep_w<<<dim3((unsigned)(prep_total / 256)), dim3(256), 0, stream>>>(
      Wk, Wv, Wb, Wg, Wo, Wcomb, Wob);
  rmsnorm_k<<<dim3(ROWS), dim3(256), 0, stream>>>(x, normw, xn);
  gemm_nt<0, 0><<<dim3(NPAD / 128, ROWS / 128), dim3(256), 0, stream>>>(
      xn, Wcomb, kvb, (float*)nullptr, (const float*)nullptr, ROWS, NPAD, D_);
  postproc<<<dim3(ROWS), dim3(64), 0, stream>>>(kvb, bb, bg, bA, gA);
  scan_k<<<dim3(64), dim3(256), 0, stream>>>(kvb, bA, gA, outb);
  gemm_nt<1, 1><<<dim3(D_ / 128, ROWS / 128), dim3(256), 0, stream>>>(
      outb, Wob, (u16*)nullptr, y, x, ROWS, D_, D_);
}

// Round 2
// 426.025 us; speedup vs baseline: 2.8414x; 2.8414x over previous
//
#include <hip/hip_runtime.h>
#include <stdint.h>

#define B_ 4
#define T_ 4096
#define D_ 1024
#define H_ 16
#define NPAD 2176            // 1024 k + 1024 v + 16 beta + 16 g + 96 zero-pad
#define ROWS (B_*T_)         // 16384

typedef __bf16 bf16x8 __attribute__((ext_vector_type(8)));
typedef float  f32x4  __attribute__((ext_vector_type(4)));
typedef unsigned short u16;
typedef u16 u16x8 __attribute__((ext_vector_type(8)));
typedef u16 u16x4 __attribute__((ext_vector_type(4)));

__device__ __forceinline__ float bf2f(u16 u){
  union { unsigned int i; float f; } x; x.i = ((unsigned int)u) << 16; return x.f;
}
__device__ __forceinline__ u16 f2bf(float f){
  union { float f; unsigned int i; } x; x.f = f;
  unsigned int r = x.i + 0x7fffu + ((x.i >> 16) & 1u);
  return (u16)(r >> 16);
}
__device__ __forceinline__ bf16x8 as_bf(u16x8 v){ union{u16x8 u; bf16x8 b;} x; x.u = v; return x.b; }

__device__ __forceinline__ void gload_lds16(const u16* g, u16* l){
  __builtin_amdgcn_global_load_lds(
      (const __attribute__((address_space(1))) unsigned int*)g,
      (__attribute__((address_space(3))) unsigned int*)l, 16, 0, 0);
}

// ---------------- weight prep ----------------
__global__ __launch_bounds__(256) void prep_w(
    const float* __restrict__ Wk, const float* __restrict__ Wv,
    const float* __restrict__ Wb, const float* __restrict__ Wg,
    const float* __restrict__ Wo, u16* __restrict__ Wcomb, u16* __restrict__ Wob)
{
  long i = (long)blockIdx.x * 256 + threadIdx.x;
  const long tot1 = (long)NPAD * D_;
  if (i < tot1) {
    long n = i >> 10, d = i & 1023;
    float v;
    if      (n < 1024) v = Wk[n * 1024 + d];
    else if (n < 2048) v = Wv[(n - 1024) * 1024 + d];
    else if (n < 2064) v = Wb[(n - 2048) * 1024 + d];
    else if (n < 2080) v = Wg[(n - 2064) * 1024 + d];
    else               v = 0.f;
    Wcomb[i] = f2bf(v);
  } else {
    long j = i - tot1;
    Wob[j] = f2bf(Wo[j]);
  }
}

// ---------------- RMSNorm ----------------
__global__ __launch_bounds__(256) void rmsnorm_k(
    const float* __restrict__ x, const float* __restrict__ w, u16* __restrict__ xn)
{
  long row = blockIdx.x;
  int tid = threadIdx.x;
  int l = tid & 63, wv = tid >> 6;
  f32x4 v = ((const f32x4*)(x + row * D_))[tid];
  float ss = v[0]*v[0] + v[1]*v[1] + v[2]*v[2] + v[3]*v[3];
  #pragma unroll
  for (int m = 1; m < 64; m <<= 1) ss += __shfl_xor(ss, m, 64);
  __shared__ float red[4];
  if (l == 0) red[wv] = ss;
  __syncthreads();
  float tot = red[0] + red[1] + red[2] + red[3];
  float inv = rsqrtf(tot * (1.f / (float)D_) + 1e-6f);
  f32x4 wv4 = ((const f32x4*)w)[tid];
  u16x4 o;
  o[0] = f2bf(v[0] * inv * wv4[0]);
  o[1] = f2bf(v[1] * inv * wv4[1]);
  o[2] = f2bf(v[2] * inv * wv4[2]);
  o[3] = f2bf(v[3] * inv * wv4[3]);
  ((u16x4*)(xn + row * D_))[tid] = o;
}

// ---------------- bf16 NT GEMM (validated round 1) ----------------
template<int RESID, int OUTF32>
__global__ __launch_bounds__(256) void gemm_nt(
    const u16* __restrict__ A, const u16* __restrict__ Bm,
    u16* __restrict__ Cb, float* __restrict__ Cf, const float* __restrict__ resid,
    int M, int N, int Kd)
{
  __shared__ __align__(16) u16 Als[128 * 32];
  __shared__ __align__(16) u16 Bls[128 * 32];
  const int tid = threadIdx.x;
  const int w = tid >> 6, l = tid & 63;
  const int wr = w >> 1, wc = w & 1;
  const int lm = l & 15, lq = l >> 4;
  const long bm0 = (long)blockIdx.y * 128;
  const long bn0 = (long)blockIdx.x * 128;

  f32x4 zero4 = {0.f, 0.f, 0.f, 0.f};
  f32x4 acc[4][4];
  #pragma unroll
  for (int i = 0; i < 4; i++)
    #pragma unroll
    for (int j = 0; j < 4; j++) acc[i][j] = zero4;

  for (int kk = 0; kk < Kd; kk += 32) {
    __syncthreads();
    #pragma unroll
    for (int it = 0; it < 2; it++) {
      int c = tid + it * 256;
      int r = c >> 2, kb = c & 3;
      const u16* ga = A  + (bm0 + r) * Kd + kk + kb * 8;
      const u16* gb = Bm + (bn0 + r) * Kd + kk + kb * 8;
      gload_lds16(ga, Als + (it * 256 + w * 64) * 8);
      gload_lds16(gb, Bls + (it * 256 + w * 64) * 8);
    }
    __syncthreads();
    bf16x8 af[4], bfr[4];
    #pragma unroll
    for (int f = 0; f < 4; f++)
      af[f] = *(const bf16x8*)(Als + (wr * 64 + f * 16 + lm) * 32 + lq * 8);
    #pragma unroll
    for (int f = 0; f < 4; f++)
      bfr[f] = *(const bf16x8*)(Bls + (wc * 64 + f * 16 + lm) * 32 + lq * 8);
    #pragma unroll
    for (int i = 0; i < 4; i++)
      #pragma unroll
      for (int j = 0; j < 4; j++)
        acc[i][j] = __builtin_amdgcn_mfma_f32_16x16x32_bf16(af[i], bfr[j], acc[i][j], 0, 0, 0);
  }

  #pragma unroll
  for (int i = 0; i < 4; i++) {
    #pragma unroll
    for (int r = 0; r < 4; r++) {
      long m = bm0 + wr * 64 + i * 16 + lq * 4 + r;
      #pragma unroll
      for (int j = 0; j < 4; j++) {
        long n = bn0 + wc * 64 + j * 16 + lm;
        float val = acc[i][j][r];
        if (RESID) val += resid[m * N + n];
        if (OUTF32) Cf[m * N + n] = val;
        else        Cb[m * N + n] = f2bf(val);
      }
    }
  }
}

// ---------------- postprocess ----------------
__global__ __launch_bounds__(64) void postproc(
    u16* __restrict__ kv, const float* __restrict__ bb, const float* __restrict__ bg,
    float* __restrict__ bArr, float* __restrict__ gArr)
{
  long row = blockIdx.x;
  int l = threadIdx.x;
  u16* rp = kv + row * NPAD;
  #pragma unroll
  for (int h = 0; h < 16; h++) {
    float xk = bf2f(rp[h * 64 + l]);
    float ss = xk * xk;
    #pragma unroll
    for (int m = 1; m < 64; m <<= 1) ss += __shfl_xor(ss, m, 64);
    float inv = 1.f / fmaxf(sqrtf(ss), 1e-12f);
    rp[h * 64 + l] = f2bf(xk * inv);
  }
  if (l < 32) {
    int hh = l & 15;
    float val = bf2f(rp[2048 + l]) + ((l < 16) ? bb[hh] : bg[hh]);
    float s = 1.f / (1.f + expf(-val));
    float* dst = (l < 16) ? bArr : gArr;
    long b = row >> 12;
    long t = row & 4095;
    dst[(b * H_ + hh) * (long)T_ + t] = s;
  }
}

// 64x64x64 NT matmul from LDS bf16 tiles (stride 72): C[m,n] += sum_k A[m,k]*B[n,k]
__device__ __forceinline__ void mm64(const u16* Ab, const u16* Bb,
                                     int lm, int lq, int wr, int wc, f32x4 acc[2][2])
{
  #pragma unroll
  for (int ks = 0; ks < 2; ++ks) {
    bf16x8 af[2], bfr[2];
    #pragma unroll
    for (int mi = 0; mi < 2; ++mi)
      af[mi] = *(const bf16x8*)(Ab + (wr*32 + mi*16 + lm)*72 + ks*32 + lq*8);
    #pragma unroll
    for (int ni = 0; ni < 2; ++ni)
      bfr[ni] = *(const bf16x8*)(Bb + (wc*32 + ni*16 + lm)*72 + ks*32 + lq*8);
    #pragma unroll
    for (int mi = 0; mi < 2; ++mi)
      #pragma unroll
      for (int ni = 0; ni < 2; ++ni)
        acc[mi][ni] = __builtin_amdgcn_mfma_f32_16x16x32_bf16(af[mi], bfr[ni], acc[mi][ni], 0, 0, 0);
  }
}

// ---------------- phase 1: per-chunk WY factors ----------------
// block = (bh, chunk). Computes P1^T, R1^T (to p1buf/r1buf), Q, M (in-place over K/V in kvb).
__global__ __launch_bounds__(256) void chunk1(
    u16* __restrict__ kv, const float* __restrict__ bArr, const float* __restrict__ gArr,
    u16* __restrict__ p1buf, u16* __restrict__ r1buf)
{
  __shared__ __align__(16) u16 Kb[64*72];
  __shared__ __align__(16) u16 Vb[64*72];     // becomes LpI after w-init
  __shared__ __align__(16) u16 Ktb[64*72];    // Khat^T: Ktb[k][s] = (aC/a_s) K[s][k]
  __shared__ __align__(16) float At[64*68];   // At[i][j] = A[j,i] (0 for j<=i)
  __shared__ __align__(16) u16 Utb[128*72];   // rows 0..63: U1^T[v][s]; 64..127: U2^T[j][s]
  __shared__ float aLS[64], ainvLS[64], bLS[64], bapLS[64];
  __shared__ float aCsh;

  const int tid = threadIdx.x;
  const int w = tid >> 6, l = tid & 63;
  const int lm = l & 15, lq = l >> 4;
  const int wr = w >> 1, wc = w & 1;
  const int bh = blockIdx.x & 63, ch = blockIdx.x >> 6;
  const int b = bh >> 4, h = bh & 15;

  const u16* kbase = kv + ((long)b*T_ + ch*64)*NPAD + h*64;
  const u16* vbase = kbase + 1024;

  // stage K, V chunk
  #pragma unroll
  for (int it = 0; it < 2; ++it) {
    int c = tid + it*256;
    int r = c >> 3, seg = (c & 7)*8;
    *(u16x8*)(Kb + r*72 + seg) = *(const u16x8*)(kbase + (long)r*NPAD + seg);
    *(u16x8*)(Vb + r*72 + seg) = *(const u16x8*)(vbase + (long)r*NPAD + seg);
  }
  // decay scan (wave 0)
  if (tid < 64) {
    float gv = gArr[(long)bh*T_ + ch*64 + tid];
    float bv = bArr[(long)bh*T_ + ch*64 + tid];
    float av = gv;
    #pragma unroll
    for (int off = 1; off < 64; off <<= 1) {
      float o = __shfl_up(av, off, 64);
      if (tid >= off) av *= o;
    }
    float ap = __shfl_up(av, 1, 64);
    if (tid == 0) ap = 1.f;
    float aC = __shfl(av, 63, 64);
    aLS[tid] = av; ainvLS[tid] = 1.f/av; bLS[tid] = bv; bapLS[tid] = bv*ap;
    if (tid == 0) aCsh = aC;
  }
  __syncthreads();

  // G = K K^T (MFMA, f32-exact gram of bf16 k)
  f32x4 gf[2][2];
  #pragma unroll
  for (int mi = 0; mi < 2; ++mi)
    #pragma unroll
    for (int ni = 0; ni < 2; ++ni) gf[mi][ni] = f32x4{0.f,0.f,0.f,0.f};
  mm64(Kb, Kb, lm, lq, wr, wc, gf);

  // Ktb[k][s] = (aC/a_s) K[s][k]
  {
    int kk_ = tid >> 2, sb = (tid & 3) * 16;
    float aC = aCsh;
    #pragma unroll
    for (int s5 = 0; s5 < 16; ++s5) {
      int s = sb + s5;
      Ktb[kk_*72 + s] = f2bf(aC * ainvLS[s] * bf2f(Kb[s*72 + kk_]));
    }
  }
  // At writes (strict lower of A, transposed)
  #pragma unroll
  for (int mi = 0; mi < 2; ++mi)
    #pragma unroll
    for (int ni = 0; ni < 2; ++ni)
      #pragma unroll
      for (int r = 0; r < 4; ++r) {
        int row = wr*32 + mi*16 + lq*4 + r, col = wc*32 + ni*16 + lm;
        At[row*68 + col] = (col > row) ? bapLS[col]*ainvLS[row]*gf[mi][ni][r] : 0.f;
      }
  // w-init in registers: thread (cg = tid>>3 cols cg*4..+3, jg = tid&7 rows jg*8..+7)
  const int cg = tid >> 3, jg = tid & 7;
  float wreg[32];
  #pragma unroll
  for (int rr = 0; rr < 8; ++rr) {
    int i = jg*8 + rr;
    u16x4 s4 = (cg < 16) ? *(const u16x4*)(Vb + i*72 + cg*4)
                         : *(const u16x4*)(Kb + i*72 + (cg-16)*4);
    float coef = (cg < 16) ? bLS[i] : bapLS[i];
    wreg[rr*4+0] = coef * bf2f(s4[0]);
    wreg[rr*4+1] = coef * bf2f(s4[1]);
    wreg[rr*4+2] = coef * bf2f(s4[2]);
    wreg[rr*4+3] = coef * bf2f(s4[3]);
  }
  __syncthreads();   // At complete; Vb dead

  // LpI = (L + I) bf16, over Vb
  u16* LpI = Vb;
  #pragma unroll
  for (int mi = 0; mi < 2; ++mi)
    #pragma unroll
    for (int ni = 0; ni < 2; ++ni)
      #pragma unroll
      for (int r = 0; r < 4; ++r) {
        int row = wr*32 + mi*16 + lq*4 + r, col = wc*32 + ni*16 + lm;
        float lv = (col < row) ? aLS[row]*ainvLS[col]*gf[mi][ni][r] : ((col == row) ? 1.f : 0.f);
        LpI[row*72 + col] = f2bf(lv);
      }

  // forward substitution: (I+A)U = W, per-wave column ownership, shfl broadcast, no barriers
  #pragma unroll 64
  for (int i = 0; i < 64; ++i) {
    int srcl = (l & 56) | (i >> 3);
    float u0 = __shfl(wreg[(i&7)*4+0], srcl, 64);
    float u1 = __shfl(wreg[(i&7)*4+1], srcl, 64);
    float u2 = __shfl(wreg[(i&7)*4+2], srcl, 64);
    float u3 = __shfl(wreg[(i&7)*4+3], srcl, 64);
    if (jg == (i >> 3)) {
      Utb[(cg*4+0)*72 + i] = f2bf(wreg[(i&7)*4+0]);
      Utb[(cg*4+1)*72 + i] = f2bf(wreg[(i&7)*4+1]);
      Utb[(cg*4+2)*72 + i] = f2bf(wreg[(i&7)*4+2]);
      Utb[(cg*4+3)*72 + i] = f2bf(wreg[(i&7)*4+3]);
    }
    f32x4 a0 = *(const f32x4*)(At + i*68 + jg*8);
    f32x4 a1 = *(const f32x4*)(At + i*68 + jg*8 + 4);
    float n0 = -u0, n1 = -u1, n2 = -u2, n3 = -u3;
    #pragma unroll
    for (int rr = 0; rr < 4; ++rr) {
      wreg[rr*4+0] = fmaf(a0[rr], n0, wreg[rr*4+0]);
      wreg[rr*4+1] = fmaf(a0[rr], n1, wreg[rr*4+1]);
      wreg[rr*4+2] = fmaf(a0[rr], n2, wreg[rr*4+2]);
      wreg[rr*4+3] = fmaf(a0[rr], n3, wreg[rr*4+3]);
    }
    #pragma unroll
    for (int rr = 0; rr < 4; ++rr) {
      wreg[(rr+4)*4+0] = fmaf(a1[rr], n0, wreg[(rr+4)*4+0]);
      wreg[(rr+4)*4+1] = fmaf(a1[rr], n1, wreg[(rr+4)*4+1]);
      wreg[(rr+4)*4+2] = fmaf(a1[rr], n2, wreg[(rr+4)*4+2]);
      wreg[(rr+4)*4+3] = fmaf(a1[rr], n3, wreg[(rr+4)*4+3]);
    }
  }
  __syncthreads();   // Utb + LpI complete

  const long pr_base = (((long)bh*64 + ch)*64);
  u16* qdst = kv + ((long)b*T_ + ch*64)*NPAD + h*64;         // Q over K-region
  u16* mdst = qdst + 1024;                                    // M over V-region
  f32x4 acc[2][2];

  // P1^T[v][i] = sum_s U1t[v][s] * LpI[i][s]
  #pragma unroll
  for (int mi = 0; mi < 2; ++mi)
    #pragma unroll
    for (int ni = 0; ni < 2; ++ni) acc[mi][ni] = f32x4{0.f,0.f,0.f,0.f};
  mm64(Utb, LpI, lm, lq, wr, wc, acc);
  #pragma unroll
  for (int mi = 0; mi < 2; ++mi)
    #pragma unroll
    for (int ni = 0; ni < 2; ++ni)
      #pragma unroll
      for (int r = 0; r < 4; ++r) {
        int row = wr*32 + mi*16 + lq*4 + r, col = wc*32 + ni*16 + lm;
        p1buf[(pr_base + row)*64 + col] = f2bf(acc[mi][ni][r]);
      }

  // Q[i][j] = a_i K[i][j] - sum_s LpI[i][s] * U2t[j][s]
  #pragma unroll
  for (int mi = 0; mi < 2; ++mi)
    #pragma unroll
    for (int ni = 0; ni < 2; ++ni) acc[mi][ni] = f32x4{0.f,0.f,0.f,0.f};
  mm64(LpI, Utb + 64*72, lm, lq, wr, wc, acc);
  #pragma unroll
  for (int mi = 0; mi < 2; ++mi)
    #pragma unroll
    for (int ni = 0; ni < 2; ++ni)
      #pragma unroll
      for (int r = 0; r < 4; ++r) {
        int row = wr*32 + mi*16 + lq*4 + r, col = wc*32 + ni*16 + lm;
        float val = aLS[row]*bf2f(Kb[row*72 + col]) - acc[mi][ni][r];
        qdst[(long)row*NPAD + col] = f2bf(val);
      }

  // R1^T[v][k] = sum_s U1t[v][s] * Ktb[k][s]
  #pragma unroll
  for (int mi = 0; mi < 2; ++mi)
    #pragma unroll
    for (int ni = 0; ni < 2; ++ni) acc[mi][ni] = f32x4{0.f,0.f,0.f,0.f};
  mm64(Utb, Ktb, lm, lq, wr, wc, acc);
  #pragma unroll
  for (int mi = 0; mi < 2; ++mi)
    #pragma unroll
    for (int ni = 0; ni < 2; ++ni)
      #pragma unroll
      for (int r = 0; r < 4; ++r) {
        int row = wr*32 + mi*16 + lq*4 + r, col = wc*32 + ni*16 + lm;
        r1buf[(pr_base + row)*64 + col] = f2bf(acc[mi][ni][r]);
      }

  // M[k][j] = aC*I - sum_s Ktb[k][s] * U2t[j][s]
  #pragma unroll
  for (int mi = 0; mi < 2; ++mi)
    #pragma unroll
    for (int ni = 0; ni < 2; ++ni) acc[mi][ni] = f32x4{0.f,0.f,0.f,0.f};
  mm64(Ktb, Utb + 64*72, lm, lq, wr, wc, acc);
  #pragma unroll
  for (int mi = 0; mi < 2; ++mi)
    #pragma unroll
    for (int ni = 0; ni < 2; ++ni)
      #pragma unroll
      for (int r = 0; r < 4; ++r) {
        int row = wr*32 + mi*16 + lq*4 + r, col = wc*32 + ni*16 + lm;
        float val = ((row == col) ? aCsh : 0.f) - acc[mi][ni][r];
        mdst[(long)row*NPAD + col] = f2bf(val);
      }
}

// ---------------- phase 2: sequential chunk recurrence ----------------
// block = (bh, vg): 16 v-rows of Z = S^T. Out^T = P1t + Z Q^T ; Z' = R1t + Z M^T.
struct PF { u16x8 qf0, qf1, mf0, mf1; u16 p1[4]; u16 r1[4]; };

__global__ __launch_bounds__(256) void chunk2(
    const u16* __restrict__ kv, const u16* __restrict__ p1buf, const u16* __restrict__ r1buf,
    u16* __restrict__ outb)
{
  __shared__ __align__(16) u16 Zb[16*72];
  __shared__ __align__(16) u16 ot[64*24];
  const int tid = threadIdx.x;
  const int wcv = tid >> 6, l = tid & 63;
  const int lm = l & 15, lq = l >> 4;
  const int bh = blockIdx.x & 63, vg = blockIdx.x >> 6;   // same-bh blocks share XCD (id mod 8 = bh mod 8)
  const int b = bh >> 4, h = bh & 15;

  for (int idx = tid; idx < 16*72/2; idx += 256) ((unsigned int*)Zb)[idx] = 0u;

  const u16* pbase = p1buf + (long)bh*64*4096;
  const u16* rbase = r1buf + (long)bh*64*4096;

  auto LOADPF = [&](int ch, PF& p){
    long rq = ((long)b*T_ + ch*64 + wcv*16 + lm)*NPAD + h*64 + lq*8;
    p.qf0 = *(const u16x8*)(kv + rq);
    p.qf1 = *(const u16x8*)(kv + rq + 32);
    p.mf0 = *(const u16x8*)(kv + rq + 1024);
    p.mf1 = *(const u16x8*)(kv + rq + 1024 + 32);
    #pragma unroll
    for (int r = 0; r < 4; ++r) {
      long pv = (long)ch*4096 + (vg*16 + lq*4 + r)*64 + wcv*16 + lm;
      p.p1[r] = pbase[pv];
      p.r1[r] = rbase[pv];
    }
  };

  PF A, Bp;
  LOADPF(0, A);
  __syncthreads();

  auto STEP = [&](int ch, PF& use, PF& pre){
    bf16x8 za0 = *(const bf16x8*)(Zb + lm*72 + lq*8);
    bf16x8 za1 = *(const bf16x8*)(Zb + lm*72 + 32 + lq*8);
    if (ch < 63) LOADPF(ch + 1, pre);
    f32x4 accO = { bf2f(use.p1[0]), bf2f(use.p1[1]), bf2f(use.p1[2]), bf2f(use.p1[3]) };
    accO = __builtin_amdgcn_mfma_f32_16x16x32_bf16(za0, as_bf(use.qf0), accO, 0, 0, 0);
    accO = __builtin_amdgcn_mfma_f32_16x16x32_bf16(za1, as_bf(use.qf1), accO, 0, 0, 0);
    f32x4 accS = { bf2f(use.r1[0]), bf2f(use.r1[1]), bf2f(use.r1[2]), bf2f(use.r1[3]) };
    accS = __builtin_amdgcn_mfma_f32_16x16x32_bf16(za0, as_bf(use.mf0), accS, 0, 0, 0);
    accS = __builtin_amdgcn_mfma_f32_16x16x32_bf16(za1, as_bf(use.mf1), accS, 0, 0, 0);
    #pragma unroll
    for (int r = 0; r < 4; ++r) ot[(wcv*16 + lm)*24 + lq*4 + r] = f2bf(accO[r]);
    __syncthreads();
    #pragma unroll
    for (int r = 0; r < 4; ++r) Zb[(lq*4 + r)*72 + wcv*16 + lm] = f2bf(accS[r]);
    {
      int i2 = tid >> 2, q4 = tid & 3;
      u16x4 ov = *(const u16x4*)(ot + i2*24 + q4*4);
      *(u16x4*)(outb + ((long)b*T_ + ch*64 + i2)*D_ + h*64 + vg*16 + q4*4) = ov;
    }
    __syncthreads();
  };

  for (int c2 = 0; c2 < 32; ++c2) {
    STEP(2*c2,     A, Bp);
    STEP(2*c2 + 1, Bp, A);
  }
}

extern "C" void kernel_launch(void* const* d_in, const int* in_sizes, int n_in,
                              void* d_out, int out_size, void* d_ws, size_t ws_size,
                              hipStream_t stream) {
  const float* x     = (const float*)d_in[0];
  const float* normw = (const float*)d_in[1];
  const float* Wk    = (const float*)d_in[2];
  const float* Wv    = (const float*)d_in[3];
  const float* Wo    = (const float*)d_in[4];
  const float* Wb    = (const float*)d_in[5];
  const float* bb    = (const float*)d_in[6];
  const float* Wg    = (const float*)d_in[7];
  const float* bg    = (const float*)d_in[8];
  float* y = (float*)d_out;

  char* ws = (char*)d_ws;
  u16* xn    = (u16*)ws;   ws += (long)ROWS * D_ * 2;      // 33.5 MB (reused as P1^T after gemm1)
  u16* Wcomb = (u16*)ws;   ws += (long)NPAD * D_ * 2;      // 4.5 MB
  u16* Wob   = (u16*)ws;   ws += (long)D_ * D_ * 2;        // 2 MB
  u16* kvb   = (u16*)ws;   ws += (long)ROWS * NPAD * 2;    // 71.3 MB (k,v -> then Q,M in place)
  float* bA  = (float*)ws; ws += (long)B_ * H_ * T_ * 4;   // 1 MB
  float* gA  = (float*)ws; ws += (long)B_ * H_ * T_ * 4;   // 1 MB
  u16* outb  = (u16*)ws;   ws += (long)ROWS * D_ * 2;      // 33.5 MB
  u16* r1b   = (u16*)ws;   ws += (long)64 * 64 * 4096 * 2; // 33.5 MB  R1^T

  const long prep_total = (long)NPAD * D_ + (long)D_ * D_;
  prep_w<<<dim3((unsigned)(prep_total / 256)), dim3(256), 0, stream>>>(
      Wk, Wv, Wb, Wg, Wo, Wcomb, Wob);
  rmsnorm_k<<<dim3(ROWS), dim3(256), 0, stream>>>(x, normw, xn);
  gemm_nt<0, 0><<<dim3(NPAD / 128, ROWS / 128), dim3(256), 0, stream>>>(
      xn, Wcomb, kvb, (float*)nullptr, (const float*)nullptr, ROWS, NPAD, D_);
  postproc<<<dim3(ROWS), dim3(64), 0, stream>>>(kvb, bb, bg, bA, gA);
  chunk1<<<dim3(4096), dim3(256), 0, stream>>>(kvb, bA, gA, xn, r1b);
  chunk2<<<dim3(256), dim3(256), 0, stream>>>(kvb, xn, r1b, outb);
  gemm_nt<1, 1><<<dim3(D_ / 128, ROWS / 128), dim3(256), 0, stream>>>(
      outb, Wob, (u16*)nullptr, y, x, ROWS, D_, D_);
}

// Round 3
// 364.053 us; speedup vs baseline: 3.3251x; 1.1702x over previous
//
#include <hip/hip_runtime.h>
#include <stdint.h>

#define B_ 4
#define T_ 4096
#define D_ 1024
#define H_ 16
#define NPAD 2176            // 1024 k + 1024 v + 16 beta + 16 g + 96 zero-pad
#define ROWS (B_*T_)         // 16384

typedef __bf16 bf16x8 __attribute__((ext_vector_type(8)));
typedef float  f32x4  __attribute__((ext_vector_type(4)));
typedef unsigned short u16;
typedef u16 u16x8 __attribute__((ext_vector_type(8)));
typedef u16 u16x4 __attribute__((ext_vector_type(4)));

__device__ __forceinline__ float bf2f(u16 u){
  union { unsigned int i; float f; } x; x.i = ((unsigned int)u) << 16; return x.f;
}
__device__ __forceinline__ u16 f2bf(float f){
  union { float f; unsigned int i; } x; x.f = f;
  unsigned int r = x.i + 0x7fffu + ((x.i >> 16) & 1u);
  return (u16)(r >> 16);
}
__device__ __forceinline__ bf16x8 as_bf(u16x8 v){ union{u16x8 u; bf16x8 b;} x; x.u = v; return x.b; }

__device__ __forceinline__ void gload_lds16(const u16* g, u16* l){
  __builtin_amdgcn_global_load_lds(
      (const __attribute__((address_space(1))) unsigned int*)g,
      (__attribute__((address_space(3))) unsigned int*)l, 16, 0, 0);
}

// ---------------- weight prep ----------------
__global__ __launch_bounds__(256) void prep_w(
    const float* __restrict__ Wk, const float* __restrict__ Wv,
    const float* __restrict__ Wb, const float* __restrict__ Wg,
    const float* __restrict__ Wo, u16* __restrict__ Wcomb, u16* __restrict__ Wob)
{
  long i = (long)blockIdx.x * 256 + threadIdx.x;
  const long tot1 = (long)NPAD * D_;
  if (i < tot1) {
    long n = i >> 10, d = i & 1023;
    float v;
    if      (n < 1024) v = Wk[n * 1024 + d];
    else if (n < 2048) v = Wv[(n - 1024) * 1024 + d];
    else if (n < 2064) v = Wb[(n - 2048) * 1024 + d];
    else if (n < 2080) v = Wg[(n - 2064) * 1024 + d];
    else               v = 0.f;
    Wcomb[i] = f2bf(v);
  } else {
    long j = i - tot1;
    Wob[j] = f2bf(Wo[j]);
  }
}

// ---------------- RMSNorm ----------------
__global__ __launch_bounds__(256) void rmsnorm_k(
    const float* __restrict__ x, const float* __restrict__ w, u16* __restrict__ xn)
{
  long row = blockIdx.x;
  int tid = threadIdx.x;
  int l = tid & 63, wv = tid >> 6;
  f32x4 v = ((const f32x4*)(x + row * D_))[tid];
  float ss = v[0]*v[0] + v[1]*v[1] + v[2]*v[2] + v[3]*v[3];
  #pragma unroll
  for (int m = 1; m < 64; m <<= 1) ss += __shfl_xor(ss, m, 64);
  __shared__ float red[4];
  if (l == 0) red[wv] = ss;
  __syncthreads();
  float tot = red[0] + red[1] + red[2] + red[3];
  float inv = rsqrtf(tot * (1.f / (float)D_) + 1e-6f);
  f32x4 wv4 = ((const f32x4*)w)[tid];
  u16x4 o;
  o[0] = f2bf(v[0] * inv * wv4[0]);
  o[1] = f2bf(v[1] * inv * wv4[1]);
  o[2] = f2bf(v[2] * inv * wv4[2]);
  o[3] = f2bf(v[3] * inv * wv4[3]);
  ((u16x4*)(xn + row * D_))[tid] = o;
}

// ---------------- bf16 NT GEMM (validated round 1; + XCD swizzle) ----------------
template<int RESID, int OUTF32>
__global__ __launch_bounds__(256) void gemm_nt(
    const u16* __restrict__ A, const u16* __restrict__ Bm,
    u16* __restrict__ Cb, float* __restrict__ Cf, const float* __restrict__ resid,
    int M, int N, int Kd)
{
  __shared__ __align__(16) u16 Als[128 * 32];
  __shared__ __align__(16) u16 Bls[128 * 32];
  const int tid = threadIdx.x;
  const int w = tid >> 6, l = tid & 63;
  const int wr = w >> 1, wc = w & 1;
  const int lm = l & 15, lq = l >> 4;

  // bijective XCD swizzle (nwg divisible by 8 for both launches)
  unsigned bid = blockIdx.y * gridDim.x + blockIdx.x;
  unsigned nwg = gridDim.x * gridDim.y;
  unsigned cpx = nwg >> 3;
  unsigned swz = (bid & 7) * cpx + (bid >> 3);
  const long bm0 = (long)(swz / gridDim.x) * 128;
  const long bn0 = (long)(swz % gridDim.x) * 128;

  f32x4 zero4 = {0.f, 0.f, 0.f, 0.f};
  f32x4 acc[4][4];
  #pragma unroll
  for (int i = 0; i < 4; i++)
    #pragma unroll
    for (int j = 0; j < 4; j++) acc[i][j] = zero4;

  for (int kk = 0; kk < Kd; kk += 32) {
    __syncthreads();
    #pragma unroll
    for (int it = 0; it < 2; it++) {
      int c = tid + it * 256;
      int r = c >> 2, kb = c & 3;
      const u16* ga = A  + (bm0 + r) * Kd + kk + kb * 8;
      const u16* gb = Bm + (bn0 + r) * Kd + kk + kb * 8;
      gload_lds16(ga, Als + (it * 256 + w * 64) * 8);
      gload_lds16(gb, Bls + (it * 256 + w * 64) * 8);
    }
    __syncthreads();
    bf16x8 af[4], bfr[4];
    #pragma unroll
    for (int f = 0; f < 4; f++)
      af[f] = *(const bf16x8*)(Als + (wr * 64 + f * 16 + lm) * 32 + lq * 8);
    #pragma unroll
    for (int f = 0; f < 4; f++)
      bfr[f] = *(const bf16x8*)(Bls + (wc * 64 + f * 16 + lm) * 32 + lq * 8);
    #pragma unroll
    for (int i = 0; i < 4; i++)
      #pragma unroll
      for (int j = 0; j < 4; j++)
        acc[i][j] = __builtin_amdgcn_mfma_f32_16x16x32_bf16(af[i], bfr[j], acc[i][j], 0, 0, 0);
  }

  #pragma unroll
  for (int i = 0; i < 4; i++) {
    #pragma unroll
    for (int r = 0; r < 4; r++) {
      long m = bm0 + wr * 64 + i * 16 + lq * 4 + r;
      #pragma unroll
      for (int j = 0; j < 4; j++) {
        long n = bn0 + wc * 64 + j * 16 + lm;
        float val = acc[i][j][r];
        if (RESID) val += resid[m * N + n];
        if (OUTF32) Cf[m * N + n] = val;
        else        Cb[m * N + n] = f2bf(val);
      }
    }
  }
}

// ---------------- postprocess ----------------
__global__ __launch_bounds__(64) void postproc(
    u16* __restrict__ kv, const float* __restrict__ bb, const float* __restrict__ bg,
    float* __restrict__ bArr, float* __restrict__ gArr)
{
  long row = blockIdx.x;
  int l = threadIdx.x;
  u16* rp = kv + row * NPAD;
  #pragma unroll
  for (int h = 0; h < 16; h++) {
    float xk = bf2f(rp[h * 64 + l]);
    float ss = xk * xk;
    #pragma unroll
    for (int m = 1; m < 64; m <<= 1) ss += __shfl_xor(ss, m, 64);
    float inv = 1.f / fmaxf(sqrtf(ss), 1e-12f);
    rp[h * 64 + l] = f2bf(xk * inv);
  }
  if (l < 32) {
    int hh = l & 15;
    float val = bf2f(rp[2048 + l]) + ((l < 16) ? bb[hh] : bg[hh]);
    float s = 1.f / (1.f + expf(-val));
    float* dst = (l < 16) ? bArr : gArr;
    long b = row >> 12;
    long t = row & 4095;
    dst[(b * H_ + hh) * (long)T_ + t] = s;
  }
}

// 64x64x64 NT matmul from LDS bf16 tiles (stride 72): C[m,n] += sum_k A[m,k]*B[n,k]
__device__ __forceinline__ void mm64(const u16* Ab, const u16* Bb,
                                     int lm, int lq, int wr, int wc, f32x4 acc[2][2])
{
  #pragma unroll
  for (int ks = 0; ks < 2; ++ks) {
    bf16x8 af[2], bfr[2];
    #pragma unroll
    for (int mi = 0; mi < 2; ++mi)
      af[mi] = *(const bf16x8*)(Ab + (wr*32 + mi*16 + lm)*72 + ks*32 + lq*8);
    #pragma unroll
    for (int ni = 0; ni < 2; ++ni)
      bfr[ni] = *(const bf16x8*)(Bb + (wc*32 + ni*16 + lm)*72 + ks*32 + lq*8);
    #pragma unroll
    for (int mi = 0; mi < 2; ++mi)
      #pragma unroll
      for (int ni = 0; ni < 2; ++ni)
        acc[mi][ni] = __builtin_amdgcn_mfma_f32_16x16x32_bf16(af[mi], bfr[ni], acc[mi][ni], 0, 0, 0);
  }
}

// ---------------- phase 1: per-chunk WY factors (blocked substitution) ----------------
// block = (bh, chunk). Computes P1^T, R1^T (to p1buf/r1buf), Q, M (in-place over K/V in kvb).
// LDS ~52.5KB -> 3 blocks/CU.
__global__ __launch_bounds__(256) void chunk1(
    u16* __restrict__ kv, const float* __restrict__ bArr, const float* __restrict__ gArr,
    u16* __restrict__ p1buf, u16* __restrict__ r1buf)
{
  __shared__ __align__(16) u16 Kb[64*72];      // K chunk [s][k]
  __shared__ __align__(16) u16 Utb[128*72];    // V staged [row][col] -> U^T [col][s]
  __shared__ __align__(16) u16 LpI[64*72];     // (L+I) bf16
  __shared__ __align__(16) u16 Abf[64*72];     // off-diag A bf16 (diag blocks zeroed) -> later Ktb
  __shared__ __align__(16) float Ad[4*16*21];  // diagonal-block A, f32, zeroed upper
  __shared__ float aLS[64], ainvLS[64], bLS[64], bapLS[64];
  __shared__ float aCsh;

  const int tid = threadIdx.x;
  const int w = tid >> 6, l = tid & 63;
  const int lm = l & 15, lq = l >> 4;
  const int wr = w >> 1, wc = w & 1;
  const int bh = blockIdx.x & 63, ch = blockIdx.x >> 6;
  const int b = bh >> 4, h = bh & 15;

  const u16* kbase = kv + ((long)b*T_ + ch*64)*NPAD + h*64;
  const u16* vbase = kbase + 1024;

  // stage K -> Kb, V -> Utb rows 0..63 ([row][col]); zero Utb rows 64..127 k-region
  #pragma unroll
  for (int it = 0; it < 2; ++it) {
    int c = tid + it*256;
    int r = c >> 3, seg = (c & 7)*8;
    *(u16x8*)(Kb  + r*72 + seg) = *(const u16x8*)(kbase + (long)r*NPAD + seg);
    *(u16x8*)(Utb + r*72 + seg) = *(const u16x8*)(vbase + (long)r*NPAD + seg);
  }
  #pragma unroll
  for (int z = 0; z < 8; ++z) {
    int idx = tid + z*256;                 // 0..2047
    int rr = idx >> 5, wd = idx & 31;
    ((unsigned int*)(Utb + (64 + rr)*72))[wd] = 0u;
  }
  // decay scan (wave 0)
  if (tid < 64) {
    float gv = gArr[(long)bh*T_ + ch*64 + tid];
    float bv = bArr[(long)bh*T_ + ch*64 + tid];
    float av = gv;
    #pragma unroll
    for (int off = 1; off < 64; off <<= 1) {
      float o = __shfl_up(av, off, 64);
      if (tid >= off) av *= o;
    }
    float ap = __shfl_up(av, 1, 64);
    if (tid == 0) ap = 1.f;
    float aC = __shfl(av, 63, 64);
    aLS[tid] = av; ainvLS[tid] = 1.f/av; bLS[tid] = bv; bapLS[tid] = bv*ap;
    if (tid == 0) aCsh = aC;
  }
  __syncthreads();   // bar1

  // G = K K^T (MFMA)
  f32x4 gf[2][2];
  #pragma unroll
  for (int mi = 0; mi < 2; ++mi)
    #pragma unroll
    for (int ni = 0; ni < 2; ++ni) gf[mi][ni] = f32x4{0.f,0.f,0.f,0.f};
  mm64(Kb, Kb, lm, lq, wr, wc, gf);

  // W-init into registers. Ownership matches MFMA C-fragment: rows bi*16+lq*4+r, cols w*32+ni*16+lm.
  float wv_[4][2][4];
  #pragma unroll
  for (int bi = 0; bi < 4; ++bi)
    #pragma unroll
    for (int ni = 0; ni < 2; ++ni) {
      int col = w*32 + ni*16 + lm;
      #pragma unroll
      for (int r = 0; r < 4; ++r) {
        int row = bi*16 + lq*4 + r;
        float sv = (col < 64) ? bf2f(Utb[row*72 + col]) : bf2f(Kb[row*72 + (col - 64)]);
        float coef = (col < 64) ? bLS[row] : bapLS[row];
        wv_[bi][ni][r] = coef * sv;
      }
    }

  // Abf / Ad / LpI from gf
  #pragma unroll
  for (int mi = 0; mi < 2; ++mi)
    #pragma unroll
    for (int ni = 0; ni < 2; ++ni)
      #pragma unroll
      for (int r = 0; r < 4; ++r) {
        int row = wr*32 + mi*16 + lq*4 + r, col = wc*32 + ni*16 + lm;
        float gvl = gf[mi][ni][r];
        int rb = row >> 4, cb = col >> 4;
        Abf[row*72 + col] = f2bf((rb > cb) ? bapLS[row]*ainvLS[col]*gvl : 0.f);
        if (rb == cb)
          Ad[(rb*16 + (row & 15))*21 + (col & 15)] =
              ((col & 15) < (row & 15)) ? bapLS[row]*ainvLS[col]*gvl : 0.f;
        LpI[row*72 + col] = f2bf((col < row) ? aLS[row]*ainvLS[col]*gvl
                                             : ((col == row) ? 1.f : 0.f));
      }
  __syncthreads();   // bar2

  // blocked forward substitution: (I+A)U = W. 4 blocks of 16; off-diag via MFMA (wave-local).
  #pragma unroll
  for (int bi = 0; bi < 4; ++bi) {
    if (bi > 0) {
      f32x4 corr[2] = { f32x4{0.f,0.f,0.f,0.f}, f32x4{0.f,0.f,0.f,0.f} };
      const int nks = (bi*16 + 31) >> 5;   // 1,1,2
      #pragma unroll
      for (int ks = 0; ks < 2; ++ks) {
        if (ks < nks) {
          bf16x8 afr = *(const bf16x8*)(Abf + (bi*16 + lm)*72 + ks*32 + lq*8);
          #pragma unroll
          for (int ni = 0; ni < 2; ++ni) {
            bf16x8 bfr = *(const bf16x8*)(Utb + (w*32 + ni*16 + lm)*72 + ks*32 + lq*8);
            corr[ni] = __builtin_amdgcn_mfma_f32_16x16x32_bf16(afr, bfr, corr[ni], 0, 0, 0);
          }
        }
      }
      #pragma unroll
      for (int ni = 0; ni < 2; ++ni)
        #pragma unroll
        for (int r = 0; r < 4; ++r) wv_[bi][ni][r] -= corr[ni][r];
    }
    // serial 16x16 unit-lower solve (f32, shfl broadcast)
    #pragma unroll
    for (int i = 0; i < 16; ++i) {
      int src = ((i >> 2) << 4) | lm;
      float u0 = __shfl(wv_[bi][0][i & 3], src, 64);
      float u1 = __shfl(wv_[bi][1][i & 3], src, 64);
      #pragma unroll
      for (int r = 0; r < 4; ++r) {
        float ad = Ad[(bi*16 + lq*4 + r)*21 + i];
        wv_[bi][0][r] = fmaf(-ad, u0, wv_[bi][0][r]);
        wv_[bi][1][r] = fmaf(-ad, u1, wv_[bi][1][r]);
      }
    }
    // write solved block to U^T
    #pragma unroll
    for (int ni = 0; ni < 2; ++ni) {
      int col = w*32 + ni*16 + lm;
      #pragma unroll
      for (int r = 0; r < 4; ++r)
        Utb[col*72 + bi*16 + lq*4 + r] = f2bf(wv_[bi][ni][r]);
    }
  }
  __syncthreads();   // bar3

  const long pr_base = (((long)bh*64 + ch)*64);
  u16* qdst = kv + ((long)b*T_ + ch*64)*NPAD + h*64;
  u16* mdst = qdst + 1024;
  f32x4 acc[2][2];

  // P1^T[v][i] = sum_s U1t[v][s] * LpI[i][s]
  #pragma unroll
  for (int mi = 0; mi < 2; ++mi)
    #pragma unroll
    for (int ni = 0; ni < 2; ++ni) acc[mi][ni] = f32x4{0.f,0.f,0.f,0.f};
  mm64(Utb, LpI, lm, lq, wr, wc, acc);
  #pragma unroll
  for (int mi = 0; mi < 2; ++mi)
    #pragma unroll
    for (int ni = 0; ni < 2; ++ni)
      #pragma unroll
      for (int r = 0; r < 4; ++r) {
        int row = wr*32 + mi*16 + lq*4 + r, col = wc*32 + ni*16 + lm;
        p1buf[(pr_base + row)*64 + col] = f2bf(acc[mi][ni][r]);
      }

  // Q[i][j] = a_i K[i][j] - sum_s LpI[i][s] * U2t[j][s]
  #pragma unroll
  for (int mi = 0; mi < 2; ++mi)
    #pragma unroll
    for (int ni = 0; ni < 2; ++ni) acc[mi][ni] = f32x4{0.f,0.f,0.f,0.f};
  mm64(LpI, Utb + 64*72, lm, lq, wr, wc, acc);
  #pragma unroll
  for (int mi = 0; mi < 2; ++mi)
    #pragma unroll
    for (int ni = 0; ni < 2; ++ni)
      #pragma unroll
      for (int r = 0; r < 4; ++r) {
        int row = wr*32 + mi*16 + lq*4 + r, col = wc*32 + ni*16 + lm;
        float val = aLS[row]*bf2f(Kb[row*72 + col]) - acc[mi][ni][r];
        qdst[(long)row*NPAD + col] = f2bf(val);
      }

  // Ktb (into Abf space): Ktb[k][s] = (aC/a_s) K[s][k]
  {
    int kk_ = tid >> 2, sb = (tid & 3) * 16;
    float aC = aCsh;
    #pragma unroll
    for (int s5 = 0; s5 < 16; ++s5) {
      int s = sb + s5;
      Abf[kk_*72 + s] = f2bf(aC * ainvLS[s] * bf2f(Kb[s*72 + kk_]));
    }
  }
  __syncthreads();   // bar4

  // R1^T[v][k] = sum_s U1t[v][s] * Ktb[k][s]
  #pragma unroll
  for (int mi = 0; mi < 2; ++mi)
    #pragma unroll
    for (int ni = 0; ni < 2; ++ni) acc[mi][ni] = f32x4{0.f,0.f,0.f,0.f};
  mm64(Utb, Abf, lm, lq, wr, wc, acc);
  #pragma unroll
  for (int mi = 0; mi < 2; ++mi)
    #pragma unroll
    for (int ni = 0; ni < 2; ++ni)
      #pragma unroll
      for (int r = 0; r < 4; ++r) {
        int row = wr*32 + mi*16 + lq*4 + r, col = wc*32 + ni*16 + lm;
        r1buf[(pr_base + row)*64 + col] = f2bf(acc[mi][ni][r]);
      }

  // M[k][j] = aC*I - sum_s Ktb[k][s] * U2t[j][s]
  #pragma unroll
  for (int mi = 0; mi < 2; ++mi)
    #pragma unroll
    for (int ni = 0; ni < 2; ++ni) acc[mi][ni] = f32x4{0.f,0.f,0.f,0.f};
  mm64(Abf, Utb + 64*72, lm, lq, wr, wc, acc);
  #pragma unroll
  for (int mi = 0; mi < 2; ++mi)
    #pragma unroll
    for (int ni = 0; ni < 2; ++ni)
      #pragma unroll
      for (int r = 0; r < 4; ++r) {
        int row = wr*32 + mi*16 + lq*4 + r, col = wc*32 + ni*16 + lm;
        float val = ((row == col) ? aCsh : 0.f) - acc[mi][ni][r];
        mdst[(long)row*NPAD + col] = f2bf(val);
      }
}

// ---------------- phase 2: sequential chunk recurrence ----------------
struct PF { u16x8 qf0, qf1, mf0, mf1; u16 p1[4]; u16 r1[4]; };

__global__ __launch_bounds__(256) void chunk2(
    const u16* __restrict__ kv, const u16* __restrict__ p1buf, const u16* __restrict__ r1buf,
    u16* __restrict__ outb)
{
  __shared__ __align__(16) u16 Zb[16*72];
  __shared__ __align__(16) u16 ot[64*24];
  const int tid = threadIdx.x;
  const int wcv = tid >> 6, l = tid & 63;
  const int lm = l & 15, lq = l >> 4;
  const int bh = blockIdx.x & 63, vg = blockIdx.x >> 6;
  const int b = bh >> 4, h = bh & 15;

  for (int idx = tid; idx < 16*72/2; idx += 256) ((unsigned int*)Zb)[idx] = 0u;

  const u16* pbase = p1buf + (long)bh*64*4096;
  const u16* rbase = r1buf + (long)bh*64*4096;

  auto LOADPF = [&](int ch, PF& p){
    long rq = ((long)b*T_ + ch*64 + wcv*16 + lm)*NPAD + h*64 + lq*8;
    p.qf0 = *(const u16x8*)(kv + rq);
    p.qf1 = *(const u16x8*)(kv + rq + 32);
    p.mf0 = *(const u16x8*)(kv + rq + 1024);
    p.mf1 = *(const u16x8*)(kv + rq + 1024 + 32);
    #pragma unroll
    for (int r = 0; r < 4; ++r) {
      long pv = (long)ch*4096 + (vg*16 + lq*4 + r)*64 + wcv*16 + lm;
      p.p1[r] = pbase[pv];
      p.r1[r] = rbase[pv];
    }
  };

  PF A, Bp;
  LOADPF(0, A);
  __syncthreads();

  auto STEP = [&](int ch, PF& use, PF& pre){
    bf16x8 za0 = *(const bf16x8*)(Zb + lm*72 + lq*8);
    bf16x8 za1 = *(const bf16x8*)(Zb + lm*72 + 32 + lq*8);
    if (ch < 63) LOADPF(ch + 1, pre);
    f32x4 accO = { bf2f(use.p1[0]), bf2f(use.p1[1]), bf2f(use.p1[2]), bf2f(use.p1[3]) };
    accO = __builtin_amdgcn_mfma_f32_16x16x32_bf16(za0, as_bf(use.qf0), accO, 0, 0, 0);
    accO = __builtin_amdgcn_mfma_f32_16x16x32_bf16(za1, as_bf(use.qf1), accO, 0, 0, 0);
    f32x4 accS = { bf2f(use.r1[0]), bf2f(use.r1[1]), bf2f(use.r1[2]), bf2f(use.r1[3]) };
    accS = __builtin_amdgcn_mfma_f32_16x16x32_bf16(za0, as_bf(use.mf0), accS, 0, 0, 0);
    accS = __builtin_amdgcn_mfma_f32_16x16x32_bf16(za1, as_bf(use.mf1), accS, 0, 0, 0);
    #pragma unroll
    for (int r = 0; r < 4; ++r) ot[(wcv*16 + lm)*24 + lq*4 + r] = f2bf(accO[r]);
    __syncthreads();
    #pragma unroll
    for (int r = 0; r < 4; ++r) Zb[(lq*4 + r)*72 + wcv*16 + lm] = f2bf(accS[r]);
    {
      int i2 = tid >> 2, q4 = tid & 3;
      u16x4 ov = *(const u16x4*)(ot + i2*24 + q4*4);
      *(u16x4*)(outb + ((long)b*T_ + ch*64 + i2)*D_ + h*64 + vg*16 + q4*4) = ov;
    }
    __syncthreads();
  };

  for (int c2 = 0; c2 < 32; ++c2) {
    STEP(2*c2,     A, Bp);
    STEP(2*c2 + 1, Bp, A);
  }
}

extern "C" void kernel_launch(void* const* d_in, const int* in_sizes, int n_in,
                              void* d_out, int out_size, void* d_ws, size_t ws_size,
                              hipStream_t stream) {
  const float* x     = (const float*)d_in[0];
  const float* normw = (const float*)d_in[1];
  const float* Wk    = (const float*)d_in[2];
  const float* Wv    = (const float*)d_in[3];
  const float* Wo    = (const float*)d_in[4];
  const float* Wb    = (const float*)d_in[5];
  const float* bb    = (const float*)d_in[6];
  const float* Wg    = (const float*)d_in[7];
  const float* bg    = (const float*)d_in[8];
  float* y = (float*)d_out;

  char* ws = (char*)d_ws;
  u16* xn    = (u16*)ws;   ws += (long)ROWS * D_ * 2;      // 33.5 MB (reused as P1^T)
  u16* Wcomb = (u16*)ws;   ws += (long)NPAD * D_ * 2;
  u16* Wob   = (u16*)ws;   ws += (long)D_ * D_ * 2;
  u16* kvb   = (u16*)ws;   ws += (long)ROWS * NPAD * 2;    // k,v -> Q,M in place
  float* bA  = (float*)ws; ws += (long)B_ * H_ * T_ * 4;
  float* gA  = (float*)ws; ws += (long)B_ * H_ * T_ * 4;
  u16* outb  = (u16*)ws;   ws += (long)ROWS * D_ * 2;
  u16* r1b   = (u16*)ws;   ws += (long)64 * 64 * 4096 * 2; // R1^T

  const long prep_total = (long)NPAD * D_ + (long)D_ * D_;
  prep_w<<<dim3((unsigned)(prep_total / 256)), dim3(256), 0, stream>>>(
      Wk, Wv, Wb, Wg, Wo, Wcomb, Wob);
  rmsnorm_k<<<dim3(ROWS), dim3(256), 0, stream>>>(x, normw, xn);
  gemm_nt<0, 0><<<dim3(NPAD / 128, ROWS / 128), dim3(256), 0, stream>>>(
      xn, Wcomb, kvb, (float*)nullptr, (const float*)nullptr, ROWS, NPAD, D_);
  postproc<<<dim3(ROWS), dim3(64), 0, stream>>>(kvb, bb, bg, bA, gA);
  chunk1<<<dim3(4096), dim3(256), 0, stream>>>(kvb, bA, gA, xn, r1b);
  chunk2<<<dim3(256), dim3(256), 0, stream>>>(kvb, xn, r1b, outb);
  gemm_nt<1, 1><<<dim3(D_ / 128, ROWS / 128), dim3(256), 0, stream>>>(
      outb, Wob, (u16*)nullptr, y, x, ROWS, D_, D_);
}

// Round 4
// 348.760 us; speedup vs baseline: 3.4709x; 1.0438x over previous
//
#include <hip/hip_runtime.h>
#include <stdint.h>

#define B_ 4
#define T_ 4096
#define D_ 1024
#define H_ 16
#define NPAD 2304            // 1024 k + 1024 v + 16 beta + 16 g + 224 zero-pad (multiple of 256)
#define ROWS (B_*T_)         // 16384

typedef __bf16 bf16x8 __attribute__((ext_vector_type(8)));
typedef float  f32x4  __attribute__((ext_vector_type(4)));
typedef unsigned short u16;
typedef u16 u16x8 __attribute__((ext_vector_type(8)));
typedef u16 u16x4 __attribute__((ext_vector_type(4)));

__device__ __forceinline__ float bf2f(u16 u){
  union { unsigned int i; float f; } x; x.i = ((unsigned int)u) << 16; return x.f;
}
__device__ __forceinline__ u16 f2bf(float f){
  union { float f; unsigned int i; } x; x.f = f;
  unsigned int r = x.i + 0x7fffu + ((x.i >> 16) & 1u);
  return (u16)(r >> 16);
}
__device__ __forceinline__ bf16x8 as_bf(u16x8 v){ union{u16x8 u; bf16x8 b;} x; x.u = v; return x.b; }

__device__ __forceinline__ void gload_lds16(const u16* g, u16* l){
  __builtin_amdgcn_global_load_lds(
      (const __attribute__((address_space(1))) unsigned int*)g,
      (__attribute__((address_space(3))) unsigned int*)l, 16, 0, 0);
}

// ---------------- weight prep ----------------
__global__ __launch_bounds__(256) void prep_w(
    const float* __restrict__ Wk, const float* __restrict__ Wv,
    const float* __restrict__ Wb, const float* __restrict__ Wg,
    const float* __restrict__ Wo, u16* __restrict__ Wcomb, u16* __restrict__ Wob)
{
  long i = (long)blockIdx.x * 256 + threadIdx.x;
  const long tot1 = (long)NPAD * D_;
  if (i < tot1) {
    long n = i >> 10, d = i & 1023;
    float v;
    if      (n < 1024) v = Wk[n * 1024 + d];
    else if (n < 2048) v = Wv[(n - 1024) * 1024 + d];
    else if (n < 2064) v = Wb[(n - 2048) * 1024 + d];
    else if (n < 2080) v = Wg[(n - 2064) * 1024 + d];
    else               v = 0.f;
    Wcomb[i] = f2bf(v);
  } else {
    long j = i - tot1;
    Wob[j] = f2bf(Wo[j]);
  }
}

// ---------------- RMSNorm ----------------
__global__ __launch_bounds__(256) void rmsnorm_k(
    const float* __restrict__ x, const float* __restrict__ w, u16* __restrict__ xn)
{
  long row = blockIdx.x;
  int tid = threadIdx.x;
  int l = tid & 63, wv = tid >> 6;
  f32x4 v = ((const f32x4*)(x + row * D_))[tid];
  float ss = v[0]*v[0] + v[1]*v[1] + v[2]*v[2] + v[3]*v[3];
  #pragma unroll
  for (int m = 1; m < 64; m <<= 1) ss += __shfl_xor(ss, m, 64);
  __shared__ float red[4];
  if (l == 0) red[wv] = ss;
  __syncthreads();
  float tot = red[0] + red[1] + red[2] + red[3];
  float inv = rsqrtf(tot * (1.f / (float)D_) + 1e-6f);
  f32x4 wv4 = ((const f32x4*)w)[tid];
  u16x4 o;
  o[0] = f2bf(v[0] * inv * wv4[0]);
  o[1] = f2bf(v[1] * inv * wv4[1]);
  o[2] = f2bf(v[2] * inv * wv4[2]);
  o[3] = f2bf(v[3] * inv * wv4[3]);
  ((u16x4*)(xn + row * D_))[tid] = o;
}

// ---------------- 256x256 deep-pipelined bf16 NT GEMM ----------------
// BK=32, 8 waves (2x4), 3 LDS buffers (96KB dynamic), prefetch distance 2 tiles,
// vmcnt(4) once per tile, XOR-swizzle (slot ^= row&3) both-sides, setprio on MFMA.
extern __shared__ f32x4 lds_dyn[];

template<int RESID, int OUTF32>
__global__ __launch_bounds__(512, 2) void gemm256(
    const u16* __restrict__ A, const u16* __restrict__ Bm,
    u16* __restrict__ Cb, float* __restrict__ Cf, const float* __restrict__ resid,
    int M, int N, int Kd)
{
  const int tid = threadIdx.x;
  const int w = tid >> 6, l = tid & 63;
  const int lm = l & 15, lq = l >> 4;
  const int wm = w >> 2, wn = w & 3;

  unsigned gx = gridDim.x;
  unsigned bid = blockIdx.y * gx + blockIdx.x;
  unsigned nwg = gx * gridDim.y;
  unsigned cpx = nwg >> 3;
  unsigned swz = (bid & 7) * cpx + (bid >> 3);
  const long bm0 = (long)(swz / gx) * 256;
  const long bn0 = (long)(swz % gx) * 256;

  char* lds = (char*)lds_dyn;

  // staging geometry: chunk c = r*512 + w*64 + l; row=c>>2, slot=c&3; source kchunk = slot^(row&3)
  int rowS[2], colS[2];
  #pragma unroll
  for (int r = 0; r < 2; ++r) {
    int c = r*512 + w*64 + l;
    int row = c >> 2, slot = c & 3;
    rowS[r] = row;
    colS[r] = (slot ^ (row & 3)) * 8;
  }

  auto STAGE_A = [&](int t, int q){
    char* base = lds + q*32768;
    long k0 = (long)t * 32;
    #pragma unroll
    for (int r = 0; r < 2; ++r)
      gload_lds16(A + (bm0 + rowS[r])*(long)Kd + k0 + colS[r],
                  (u16*)(base + (r*512 + w*64)*16));
  };
  auto STAGE_B = [&](int t, int q){
    char* base = lds + q*32768 + 16384;
    long k0 = (long)t * 32;
    #pragma unroll
    for (int r = 0; r < 2; ++r)
      gload_lds16(Bm + (bn0 + rowS[r])*(long)Kd + k0 + colS[r],
                  (u16*)(base + (r*512 + w*64)*16));
  };

  f32x4 acc[8][4];
  #pragma unroll
  for (int i = 0; i < 8; ++i)
    #pragma unroll
    for (int j = 0; j < 4; ++j) acc[i][j] = f32x4{0.f,0.f,0.f,0.f};

  const int NT = Kd >> 5;     // 32
  STAGE_A(0, 0); STAGE_B(0, 0);
  STAGE_A(1, 1); STAGE_B(1, 1);

  for (int t = 0; t < NT; ++t) {
    int q  = t % 3;
    int qn = (t + 2) % 3;
    int tn = (t + 2 < NT) ? (t + 2) : (NT - 1);

    asm volatile("s_waitcnt vmcnt(4)" ::: "memory");
    __builtin_amdgcn_s_barrier();
    asm volatile("" ::: "memory");

    const char* Ab = lds + q*32768;
    const char* Bb = Ab + 16384;

    bf16x8 bfr[4];
    #pragma unroll
    for (int nf = 0; nf < 4; ++nf) {
      int rr = wn*64 + nf*16 + lm;
      bfr[nf] = *(const bf16x8*)(Bb + rr*64 + (((unsigned)lq << 4) ^ ((unsigned)(rr & 3) << 4)));
    }
    bf16x8 afr[4];
    #pragma unroll
    for (int mf = 0; mf < 4; ++mf) {
      int rr = wm*128 + mf*16 + lm;
      afr[mf] = *(const bf16x8*)(Ab + rr*64 + (((unsigned)lq << 4) ^ ((unsigned)(rr & 3) << 4)));
    }
    STAGE_A(tn, qn);

    __builtin_amdgcn_s_setprio(1);
    #pragma unroll
    for (int mf = 0; mf < 4; ++mf)
      #pragma unroll
      for (int nf = 0; nf < 4; ++nf)
        acc[mf][nf] = __builtin_amdgcn_mfma_f32_16x16x32_bf16(afr[mf], bfr[nf], acc[mf][nf], 0, 0, 0);
    __builtin_amdgcn_s_setprio(0);

    __builtin_amdgcn_s_barrier();
    asm volatile("" ::: "memory");

    #pragma unroll
    for (int mf = 0; mf < 4; ++mf) {
      int rr = wm*128 + 64 + mf*16 + lm;
      afr[mf] = *(const bf16x8*)(Ab + rr*64 + (((unsigned)lq << 4) ^ ((unsigned)(rr & 3) << 4)));
    }
    STAGE_B(tn, qn);

    __builtin_amdgcn_s_setprio(1);
    #pragma unroll
    for (int mf = 0; mf < 4; ++mf)
      #pragma unroll
      for (int nf = 0; nf < 4; ++nf)
        acc[4+mf][nf] = __builtin_amdgcn_mfma_f32_16x16x32_bf16(afr[mf], bfr[nf], acc[4+mf][nf], 0, 0, 0);
    __builtin_amdgcn_s_setprio(0);
  }

  // epilogue
  #pragma unroll
  for (int mf = 0; mf < 8; ++mf) {
    #pragma unroll
    for (int r = 0; r < 4; ++r) {
      long m = bm0 + wm*128 + mf*16 + lq*4 + r;
      #pragma unroll
      for (int nf = 0; nf < 4; ++nf) {
        long n = bn0 + wn*64 + nf*16 + lm;
        float val = acc[mf][nf][r];
        if (RESID) val += resid[m * N + n];
        if (OUTF32) Cf[m * N + n] = val;
        else        Cb[m * N + n] = f2bf(val);
      }
    }
  }
}

// ---------------- fallback bf16 NT GEMM (validated, 128^2) ----------------
template<int RESID, int OUTF32>
__global__ __launch_bounds__(256) void gemm_nt(
    const u16* __restrict__ A, const u16* __restrict__ Bm,
    u16* __restrict__ Cb, float* __restrict__ Cf, const float* __restrict__ resid,
    int M, int N, int Kd)
{
  __shared__ __align__(16) u16 Als[128 * 32];
  __shared__ __align__(16) u16 Bls[128 * 32];
  const int tid = threadIdx.x;
  const int w = tid >> 6, l = tid & 63;
  const int wr = w >> 1, wc = w & 1;
  const int lm = l & 15, lq = l >> 4;

  unsigned bid = blockIdx.y * gridDim.x + blockIdx.x;
  unsigned nwg = gridDim.x * gridDim.y;
  unsigned cpx = nwg >> 3;
  unsigned swz = (bid & 7) * cpx + (bid >> 3);
  const long bm0 = (long)(swz / gridDim.x) * 128;
  const long bn0 = (long)(swz % gridDim.x) * 128;

  f32x4 zero4 = {0.f, 0.f, 0.f, 0.f};
  f32x4 acc[4][4];
  #pragma unroll
  for (int i = 0; i < 4; i++)
    #pragma unroll
    for (int j = 0; j < 4; j++) acc[i][j] = zero4;

  for (int kk = 0; kk < Kd; kk += 32) {
    __syncthreads();
    #pragma unroll
    for (int it = 0; it < 2; it++) {
      int c = tid + it * 256;
      int r = c >> 2, kb = c & 3;
      const u16* ga = A  + (bm0 + r) * Kd + kk + kb * 8;
      const u16* gb = Bm + (bn0 + r) * Kd + kk + kb * 8;
      gload_lds16(ga, Als + (it * 256 + w * 64) * 8);
      gload_lds16(gb, Bls + (it * 256 + w * 64) * 8);
    }
    __syncthreads();
    bf16x8 af[4], bfr[4];
    #pragma unroll
    for (int f = 0; f < 4; f++)
      af[f] = *(const bf16x8*)(Als + (wr * 64 + f * 16 + lm) * 32 + lq * 8);
    #pragma unroll
    for (int f = 0; f < 4; f++)
      bfr[f] = *(const bf16x8*)(Bls + (wc * 64 + f * 16 + lm) * 32 + lq * 8);
    #pragma unroll
    for (int i = 0; i < 4; i++)
      #pragma unroll
      for (int j = 0; j < 4; j++)
        acc[i][j] = __builtin_amdgcn_mfma_f32_16x16x32_bf16(af[i], bfr[j], acc[i][j], 0, 0, 0);
  }

  #pragma unroll
  for (int i = 0; i < 4; i++) {
    #pragma unroll
    for (int r = 0; r < 4; r++) {
      long m = bm0 + wr * 64 + i * 16 + lq * 4 + r;
      #pragma unroll
      for (int j = 0; j < 4; j++) {
        long n = bn0 + wc * 64 + j * 16 + lm;
        float val = acc[i][j][r];
        if (RESID) val += resid[m * N + n];
        if (OUTF32) Cf[m * N + n] = val;
        else        Cb[m * N + n] = f2bf(val);
      }
    }
  }
}

// ---------------- postprocess ----------------
__global__ __launch_bounds__(64) void postproc(
    u16* __restrict__ kv, const float* __restrict__ bb, const float* __restrict__ bg,
    float* __restrict__ bArr, float* __restrict__ gArr)
{
  long row = blockIdx.x;
  int l = threadIdx.x;
  u16* rp = kv + row * NPAD;
  #pragma unroll
  for (int h = 0; h < 16; h++) {
    float xk = bf2f(rp[h * 64 + l]);
    float ss = xk * xk;
    #pragma unroll
    for (int m = 1; m < 64; m <<= 1) ss += __shfl_xor(ss, m, 64);
    float inv = 1.f / fmaxf(sqrtf(ss), 1e-12f);
    rp[h * 64 + l] = f2bf(xk * inv);
  }
  if (l < 32) {
    int hh = l & 15;
    float val = bf2f(rp[2048 + l]) + ((l < 16) ? bb[hh] : bg[hh]);
    float s = 1.f / (1.f + expf(-val));
    float* dst = (l < 16) ? bArr : gArr;
    long b = row >> 12;
    long t = row & 4095;
    dst[(b * H_ + hh) * (long)T_ + t] = s;
  }
}

// 64x64x64 NT matmul from LDS bf16 tiles (stride 72)
__device__ __forceinline__ void mm64(const u16* Ab, const u16* Bb,
                                     int lm, int lq, int wr, int wc, f32x4 acc[2][2])
{
  #pragma unroll
  for (int ks = 0; ks < 2; ++ks) {
    bf16x8 af[2], bfr[2];
    #pragma unroll
    for (int mi = 0; mi < 2; ++mi)
      af[mi] = *(const bf16x8*)(Ab + (wr*32 + mi*16 + lm)*72 + ks*32 + lq*8);
    #pragma unroll
    for (int ni = 0; ni < 2; ++ni)
      bfr[ni] = *(const bf16x8*)(Bb + (wc*32 + ni*16 + lm)*72 + ks*32 + lq*8);
    #pragma unroll
    for (int mi = 0; mi < 2; ++mi)
      #pragma unroll
      for (int ni = 0; ni < 2; ++ni)
        acc[mi][ni] = __builtin_amdgcn_mfma_f32_16x16x32_bf16(af[mi], bfr[ni], acc[mi][ni], 0, 0, 0);
  }
}

// ---------------- phase 1: per-chunk WY factors (blocked substitution) ----------------
__global__ __launch_bounds__(256) void chunk1(
    u16* __restrict__ kv, const float* __restrict__ bArr, const float* __restrict__ gArr,
    u16* __restrict__ p1buf, u16* __restrict__ r1buf)
{
  __shared__ __align__(16) u16 Kb[64*72];
  __shared__ __align__(16) u16 Utb[128*72];
  __shared__ __align__(16) u16 LpI[64*72];
  __shared__ __align__(16) u16 Abf[64*72];
  __shared__ __align__(16) float Ad[4*16*21];
  __shared__ float aLS[64], ainvLS[64], bLS[64], bapLS[64];
  __shared__ float aCsh;

  const int tid = threadIdx.x;
  const int w = tid >> 6, l = tid & 63;
  const int lm = l & 15, lq = l >> 4;
  const int wr = w >> 1, wc = w & 1;
  const int bh = blockIdx.x & 63, ch = blockIdx.x >> 6;
  const int b = bh >> 4, h = bh & 15;

  const u16* kbase = kv + ((long)b*T_ + ch*64)*NPAD + h*64;
  const u16* vbase = kbase + 1024;

  #pragma unroll
  for (int it = 0; it < 2; ++it) {
    int c = tid + it*256;
    int r = c >> 3, seg = (c & 7)*8;
    *(u16x8*)(Kb  + r*72 + seg) = *(const u16x8*)(kbase + (long)r*NPAD + seg);
    *(u16x8*)(Utb + r*72 + seg) = *(const u16x8*)(vbase + (long)r*NPAD + seg);
  }
  #pragma unroll
  for (int z = 0; z < 8; ++z) {
    int idx = tid + z*256;
    int rr = idx >> 5, wd = idx & 31;
    ((unsigned int*)(Utb + (64 + rr)*72))[wd] = 0u;
  }
  if (tid < 64) {
    float gv = gArr[(long)bh*T_ + ch*64 + tid];
    float bv = bArr[(long)bh*T_ + ch*64 + tid];
    float av = gv;
    #pragma unroll
    for (int off = 1; off < 64; off <<= 1) {
      float o = __shfl_up(av, off, 64);
      if (tid >= off) av *= o;
    }
    float ap = __shfl_up(av, 1, 64);
    if (tid == 0) ap = 1.f;
    float aC = __shfl(av, 63, 64);
    aLS[tid] = av; ainvLS[tid] = 1.f/av; bLS[tid] = bv; bapLS[tid] = bv*ap;
    if (tid == 0) aCsh = aC;
  }
  __syncthreads();

  f32x4 gf[2][2];
  #pragma unroll
  for (int mi = 0; mi < 2; ++mi)
    #pragma unroll
    for (int ni = 0; ni < 2; ++ni) gf[mi][ni] = f32x4{0.f,0.f,0.f,0.f};
  mm64(Kb, Kb, lm, lq, wr, wc, gf);

  float wv_[4][2][4];
  #pragma unroll
  for (int bi = 0; bi < 4; ++bi)
    #pragma unroll
    for (int ni = 0; ni < 2; ++ni) {
      int col = w*32 + ni*16 + lm;
      #pragma unroll
      for (int r = 0; r < 4; ++r) {
        int row = bi*16 + lq*4 + r;
        float sv = (col < 64) ? bf2f(Utb[row*72 + col]) : bf2f(Kb[row*72 + (col - 64)]);
        float coef = (col < 64) ? bLS[row] : bapLS[row];
        wv_[bi][ni][r] = coef * sv;
      }
    }

  #pragma unroll
  for (int mi = 0; mi < 2; ++mi)
    #pragma unroll
    for (int ni = 0; ni < 2; ++ni)
      #pragma unroll
      for (int r = 0; r < 4; ++r) {
        int row = wr*32 + mi*16 + lq*4 + r, col = wc*32 + ni*16 + lm;
        float gvl = gf[mi][ni][r];
        int rb = row >> 4, cb = col >> 4;
        Abf[row*72 + col] = f2bf((rb > cb) ? bapLS[row]*ainvLS[col]*gvl : 0.f);
        if (rb == cb)
          Ad[(rb*16 + (row & 15))*21 + (col & 15)] =
              ((col & 15) < (row & 15)) ? bapLS[row]*ainvLS[col]*gvl : 0.f;
        LpI[row*72 + col] = f2bf((col < row) ? aLS[row]*ainvLS[col]*gvl
                                             : ((col == row) ? 1.f : 0.f));
      }
  __syncthreads();

  #pragma unroll
  for (int bi = 0; bi < 4; ++bi) {
    if (bi > 0) {
      f32x4 corr[2] = { f32x4{0.f,0.f,0.f,0.f}, f32x4{0.f,0.f,0.f,0.f} };
      const int nks = (bi*16 + 31) >> 5;
      #pragma unroll
      for (int ks = 0; ks < 2; ++ks) {
        if (ks < nks) {
          bf16x8 afr = *(const bf16x8*)(Abf + (bi*16 + lm)*72 + ks*32 + lq*8);
          #pragma unroll
          for (int ni = 0; ni < 2; ++ni) {
            bf16x8 bfr = *(const bf16x8*)(Utb + (w*32 + ni*16 + lm)*72 + ks*32 + lq*8);
            corr[ni] = __builtin_amdgcn_mfma_f32_16x16x32_bf16(afr, bfr, corr[ni], 0, 0, 0);
          }
        }
      }
      #pragma unroll
      for (int ni = 0; ni < 2; ++ni)
        #pragma unroll
        for (int r = 0; r < 4; ++r) wv_[bi][ni][r] -= corr[ni][r];
    }
    #pragma unroll
    for (int i = 0; i < 16; ++i) {
      int src = ((i >> 2) << 4) | lm;
      float u0 = __shfl(wv_[bi][0][i & 3], src, 64);
      float u1 = __shfl(wv_[bi][1][i & 3], src, 64);
      #pragma unroll
      for (int r = 0; r < 4; ++r) {
        float ad = Ad[(bi*16 + lq*4 + r)*21 + i];
        wv_[bi][0][r] = fmaf(-ad, u0, wv_[bi][0][r]);
        wv_[bi][1][r] = fmaf(-ad, u1, wv_[bi][1][r]);
      }
    }
    #pragma unroll
    for (int ni = 0; ni < 2; ++ni) {
      int col = w*32 + ni*16 + lm;
      #pragma unroll
      for (int r = 0; r < 4; ++r)
        Utb[col*72 + bi*16 + lq*4 + r] = f2bf(wv_[bi][ni][r]);
    }
  }
  __syncthreads();

  const long pr_base = (((long)bh*64 + ch)*64);
  u16* qdst = kv + ((long)b*T_ + ch*64)*NPAD + h*64;
  u16* mdst = qdst + 1024;
  f32x4 acc[2][2];

  #pragma unroll
  for (int mi = 0; mi < 2; ++mi)
    #pragma unroll
    for (int ni = 0; ni < 2; ++ni) acc[mi][ni] = f32x4{0.f,0.f,0.f,0.f};
  mm64(Utb, LpI, lm, lq, wr, wc, acc);
  #pragma unroll
  for (int mi = 0; mi < 2; ++mi)
    #pragma unroll
    for (int ni = 0; ni < 2; ++ni)
      #pragma unroll
      for (int r = 0; r < 4; ++r) {
        int row = wr*32 + mi*16 + lq*4 + r, col = wc*32 + ni*16 + lm;
        p1buf[(pr_base + row)*64 + col] = f2bf(acc[mi][ni][r]);
      }

  #pragma unroll
  for (int mi = 0; mi < 2; ++mi)
    #pragma unroll
    for (int ni = 0; ni < 2; ++ni) acc[mi][ni] = f32x4{0.f,0.f,0.f,0.f};
  mm64(LpI, Utb + 64*72, lm, lq, wr, wc, acc);
  #pragma unroll
  for (int mi = 0; mi < 2; ++mi)
    #pragma unroll
    for (int ni = 0; ni < 2; ++ni)
      #pragma unroll
      for (int r = 0; r < 4; ++r) {
        int row = wr*32 + mi*16 + lq*4 + r, col = wc*32 + ni*16 + lm;
        float val = aLS[row]*bf2f(Kb[row*72 + col]) - acc[mi][ni][r];
        qdst[(long)row*NPAD + col] = f2bf(val);
      }

  {
    int kk_ = tid >> 2, sb = (tid & 3) * 16;
    float aC = aCsh;
    #pragma unroll
    for (int s5 = 0; s5 < 16; ++s5) {
      int s = sb + s5;
      Abf[kk_*72 + s] = f2bf(aC * ainvLS[s] * bf2f(Kb[s*72 + kk_]));
    }
  }
  __syncthreads();

  #pragma unroll
  for (int mi = 0; mi < 2; ++mi)
    #pragma unroll
    for (int ni = 0; ni < 2; ++ni) acc[mi][ni] = f32x4{0.f,0.f,0.f,0.f};
  mm64(Utb, Abf, lm, lq, wr, wc, acc);
  #pragma unroll
  for (int mi = 0; mi < 2; ++mi)
    #pragma unroll
    for (int ni = 0; ni < 2; ++ni)
      #pragma unroll
      for (int r = 0; r < 4; ++r) {
        int row = wr*32 + mi*16 + lq*4 + r, col = wc*32 + ni*16 + lm;
        r1buf[(pr_base + row)*64 + col] = f2bf(acc[mi][ni][r]);
      }

  #pragma unroll
  for (int mi = 0; mi < 2; ++mi)
    #pragma unroll
    for (int ni = 0; ni < 2; ++ni) acc[mi][ni] = f32x4{0.f,0.f,0.f,0.f};
  mm64(Abf, Utb + 64*72, lm, lq, wr, wc, acc);
  #pragma unroll
  for (int mi = 0; mi < 2; ++mi)
    #pragma unroll
    for (int ni = 0; ni < 2; ++ni)
      #pragma unroll
      for (int r = 0; r < 4; ++r) {
        int row = wr*32 + mi*16 + lq*4 + r, col = wc*32 + ni*16 + lm;
        float val = ((row == col) ? aCsh : 0.f) - acc[mi][ni][r];
        mdst[(long)row*NPAD + col] = f2bf(val);
      }
}

// ---------------- phase 2: sequential chunk recurrence ----------------
struct PF { u16x8 qf0, qf1, mf0, mf1; u16 p1[4]; u16 r1[4]; };

__global__ __launch_bounds__(256) void chunk2(
    const u16* __restrict__ kv, const u16* __restrict__ p1buf, const u16* __restrict__ r1buf,
    u16* __restrict__ outb)
{
  __shared__ __align__(16) u16 Zb[16*72];
  __shared__ __align__(16) u16 ot[64*24];
  const int tid = threadIdx.x;
  const int wcv = tid >> 6, l = tid & 63;
  const int lm = l & 15, lq = l >> 4;
  const int bh = blockIdx.x & 63, vg = blockIdx.x >> 6;
  const int b = bh >> 4, h = bh & 15;

  for (int idx = tid; idx < 16*72/2; idx += 256) ((unsigned int*)Zb)[idx] = 0u;

  const u16* pbase = p1buf + (long)bh*64*4096;
  const u16* rbase = r1buf + (long)bh*64*4096;

  auto LOADPF = [&](int ch, PF& p){
    long rq = ((long)b*T_ + ch*64 + wcv*16 + lm)*NPAD + h*64 + lq*8;
    p.qf0 = *(const u16x8*)(kv + rq);
    p.qf1 = *(const u16x8*)(kv + rq + 32);
    p.mf0 = *(const u16x8*)(kv + rq + 1024);
    p.mf1 = *(const u16x8*)(kv + rq + 1024 + 32);
    #pragma unroll
    for (int r = 0; r < 4; ++r) {
      long pv = (long)ch*4096 + (vg*16 + lq*4 + r)*64 + wcv*16 + lm;
      p.p1[r] = pbase[pv];
      p.r1[r] = rbase[pv];
    }
  };

  PF A, Bp;
  LOADPF(0, A);
  __syncthreads();

  auto STEP = [&](int ch, PF& use, PF& pre){
    bf16x8 za0 = *(const bf16x8*)(Zb + lm*72 + lq*8);
    bf16x8 za1 = *(const bf16x8*)(Zb + lm*72 + 32 + lq*8);
    if (ch < 63) LOADPF(ch + 1, pre);
    f32x4 accO = { bf2f(use.p1[0]), bf2f(use.p1[1]), bf2f(use.p1[2]), bf2f(use.p1[3]) };
    accO = __builtin_amdgcn_mfma_f32_16x16x32_bf16(za0, as_bf(use.qf0), accO, 0, 0, 0);
    accO = __builtin_amdgcn_mfma_f32_16x16x32_bf16(za1, as_bf(use.qf1), accO, 0, 0, 0);
    f32x4 accS = { bf2f(use.r1[0]), bf2f(use.r1[1]), bf2f(use.r1[2]), bf2f(use.r1[3]) };
    accS = __builtin_amdgcn_mfma_f32_16x16x32_bf16(za0, as_bf(use.mf0), accS, 0, 0, 0);
    accS = __builtin_amdgcn_mfma_f32_16x16x32_bf16(za1, as_bf(use.mf1), accS, 0, 0, 0);
    #pragma unroll
    for (int r = 0; r < 4; ++r) ot[(wcv*16 + lm)*24 + lq*4 + r] = f2bf(accO[r]);
    __syncthreads();
    #pragma unroll
    for (int r = 0; r < 4; ++r) Zb[(lq*4 + r)*72 + wcv*16 + lm] = f2bf(accS[r]);
    {
      int i2 = tid >> 2, q4 = tid & 3;
      u16x4 ov = *(const u16x4*)(ot + i2*24 + q4*4);
      *(u16x4*)(outb + ((long)b*T_ + ch*64 + i2)*D_ + h*64 + vg*16 + q4*4) = ov;
    }
    __syncthreads();
  };

  for (int c2 = 0; c2 < 32; ++c2) {
    STEP(2*c2,     A, Bp);
    STEP(2*c2 + 1, Bp, A);
  }
}

extern "C" void kernel_launch(void* const* d_in, const int* in_sizes, int n_in,
                              void* d_out, int out_size, void* d_ws, size_t ws_size,
                              hipStream_t stream) {
  const float* x     = (const float*)d_in[0];
  const float* normw = (const float*)d_in[1];
  const float* Wk    = (const float*)d_in[2];
  const float* Wv    = (const float*)d_in[3];
  const float* Wo    = (const float*)d_in[4];
  const float* Wb    = (const float*)d_in[5];
  const float* bb    = (const float*)d_in[6];
  const float* Wg    = (const float*)d_in[7];
  const float* bg    = (const float*)d_in[8];
  float* y = (float*)d_out;

  char* ws = (char*)d_ws;
  u16* xn    = (u16*)ws;   ws += (long)ROWS * D_ * 2;      // 33.5 MB (reused as P1^T)
  u16* Wcomb = (u16*)ws;   ws += (long)NPAD * D_ * 2;      // 4.7 MB
  u16* Wob   = (u16*)ws;   ws += (long)D_ * D_ * 2;        // 2 MB
  u16* kvb   = (u16*)ws;   ws += (long)ROWS * NPAD * 2;    // 75.5 MB (k,v -> Q,M in place)
  float* bA  = (float*)ws; ws += (long)B_ * H_ * T_ * 4;
  float* gA  = (float*)ws; ws += (long)B_ * H_ * T_ * 4;
  u16* outb  = (u16*)ws;   ws += (long)ROWS * D_ * 2;
  u16* r1b   = (u16*)ws;   ws += (long)64 * 64 * 4096 * 2; // R1^T

  const int LDSB = 3 * 32768;
  bool big = true;
  if (hipFuncSetAttribute(reinterpret_cast<const void*>(gemm256<0,0>),
        hipFuncAttributeMaxDynamicSharedMemorySize, LDSB) != hipSuccess) big = false;
  if (hipFuncSetAttribute(reinterpret_cast<const void*>(gemm256<1,1>),
        hipFuncAttributeMaxDynamicSharedMemorySize, LDSB) != hipSuccess) big = false;

  const long prep_total = (long)NPAD * D_ + (long)D_ * D_;
  prep_w<<<dim3((unsigned)(prep_total / 256)), dim3(256), 0, stream>>>(
      Wk, Wv, Wb, Wg, Wo, Wcomb, Wob);
  rmsnorm_k<<<dim3(ROWS), dim3(256), 0, stream>>>(x, normw, xn);
  if (big)
    gemm256<0, 0><<<dim3(NPAD / 256, ROWS / 256), dim3(512), LDSB, stream>>>(
        xn, Wcomb, kvb, (float*)nullptr, (const float*)nullptr, ROWS, NPAD, D_);
  else
    gemm_nt<0, 0><<<dim3(NPAD / 128, ROWS / 128), dim3(256), 0, stream>>>(
        xn, Wcomb, kvb, (float*)nullptr, (const float*)nullptr, ROWS, NPAD, D_);
  postproc<<<dim3(ROWS), dim3(64), 0, stream>>>(kvb, bb, bg, bA, gA);
  chunk1<<<dim3(4096), dim3(256), 0, stream>>>(kvb, bA, gA, xn, r1b);
  chunk2<<<dim3(256), dim3(256), 0, stream>>>(kvb, xn, r1b, outb);
  if (big)
    gemm256<1, 1><<<dim3(D_ / 256, ROWS / 256), dim3(512), LDSB, stream>>>(
        outb, Wob, (u16*)nullptr, y, x, ROWS, D_, D_);
  else
    gemm_nt<1, 1><<<dim3(D_ / 128, ROWS / 128), dim3(256), 0, stream>>>(
        outb, Wob, (u16*)nullptr, y, x, ROWS, D_, D_);
}

// Round 5
// 348.679 us; speedup vs baseline: 3.4717x; 1.0002x over previous
//
#include <hip/hip_runtime.h>
#include <stdint.h>

#define B_ 4
#define T_ 4096
#define D_ 1024
#define H_ 16
#define NPAD 2304            // 1024 k + 1024 v + 16 beta + 16 g + 224 zero-pad (multiple of 256)
#define ROWS (B_*T_)         // 16384

typedef __bf16 bf16x8 __attribute__((ext_vector_type(8)));
typedef float  f32x4  __attribute__((ext_vector_type(4)));
typedef unsigned short u16;
typedef u16 u16x8 __attribute__((ext_vector_type(8)));
typedef u16 u16x4 __attribute__((ext_vector_type(4)));

__device__ __forceinline__ float bf2f(u16 u){
  union { unsigned int i; float f; } x; x.i = ((unsigned int)u) << 16; return x.f;
}
__device__ __forceinline__ u16 f2bf(float f){
  union { float f; unsigned int i; } x; x.f = f;
  unsigned int r = x.i + 0x7fffu + ((x.i >> 16) & 1u);
  return (u16)(r >> 16);
}
__device__ __forceinline__ bf16x8 as_bf(u16x8 v){ union{u16x8 u; bf16x8 b;} x; x.u = v; return x.b; }

__device__ __forceinline__ void gload_lds16(const u16* g, u16* l){
  __builtin_amdgcn_global_load_lds(
      (const __attribute__((address_space(1))) unsigned int*)g,
      (__attribute__((address_space(3))) unsigned int*)l, 16, 0, 0);
}

// ---------------- weight prep ----------------
__global__ __launch_bounds__(256) void prep_w(
    const float* __restrict__ Wk, const float* __restrict__ Wv,
    const float* __restrict__ Wb, const float* __restrict__ Wg,
    const float* __restrict__ Wo, u16* __restrict__ Wcomb, u16* __restrict__ Wob)
{
  long i = (long)blockIdx.x * 256 + threadIdx.x;
  const long tot1 = (long)NPAD * D_;
  if (i < tot1) {
    long n = i >> 10, d = i & 1023;
    float v;
    if      (n < 1024) v = Wk[n * 1024 + d];
    else if (n < 2048) v = Wv[(n - 1024) * 1024 + d];
    else if (n < 2064) v = Wb[(n - 2048) * 1024 + d];
    else if (n < 2080) v = Wg[(n - 2064) * 1024 + d];
    else               v = 0.f;
    Wcomb[i] = f2bf(v);
  } else {
    long j = i - tot1;
    Wob[j] = f2bf(Wo[j]);
  }
}

// ---------------- RMSNorm ----------------
__global__ __launch_bounds__(256) void rmsnorm_k(
    const float* __restrict__ x, const float* __restrict__ w, u16* __restrict__ xn)
{
  long row = blockIdx.x;
  int tid = threadIdx.x;
  int l = tid & 63, wv = tid >> 6;
  f32x4 v = ((const f32x4*)(x + row * D_))[tid];
  float ss = v[0]*v[0] + v[1]*v[1] + v[2]*v[2] + v[3]*v[3];
  #pragma unroll
  for (int m = 1; m < 64; m <<= 1) ss += __shfl_xor(ss, m, 64);
  __shared__ float red[4];
  if (l == 0) red[wv] = ss;
  __syncthreads();
  float tot = red[0] + red[1] + red[2] + red[3];
  float inv = rsqrtf(tot * (1.f / (float)D_) + 1e-6f);
  f32x4 wv4 = ((const f32x4*)w)[tid];
  u16x4 o;
  o[0] = f2bf(v[0] * inv * wv4[0]);
  o[1] = f2bf(v[1] * inv * wv4[1]);
  o[2] = f2bf(v[2] * inv * wv4[2]);
  o[3] = f2bf(v[3] * inv * wv4[3]);
  ((u16x4*)(xn + row * D_))[tid] = o;
}

// ---------------- 256x256 deep-pipelined bf16 NT GEMM ----------------
// BK=32, 8 waves (2x4), 3 LDS buffers (96KB dynamic), prefetch distance 2,
// ONE barrier per tile, vmcnt(4) counted (never drained), uniform-bank swizzle
// f(row)=(row>>1)&3, batched 12 ds_read -> 32 MFMA (setprio).
extern __shared__ f32x4 lds_dyn[];

template<int RESID, int OUTF32>
__global__ __launch_bounds__(512, 2) void gemm256(
    const u16* __restrict__ A, const u16* __restrict__ Bm,
    u16* __restrict__ Cb, float* __restrict__ Cf, const float* __restrict__ resid,
    int M, int N, int Kd)
{
  const int tid = threadIdx.x;
  const int w = tid >> 6, l = tid & 63;
  const int lm = l & 15, lq = l >> 4;
  const int wm = w >> 2, wn = w & 3;

  unsigned gx = gridDim.x;
  unsigned bid = blockIdx.y * gx + blockIdx.x;
  unsigned nwg = gx * gridDim.y;
  unsigned cpx = nwg >> 3;
  unsigned swz = (bid & 7) * cpx + (bid >> 3);
  const long bm0 = (long)(swz / gx) * 256;
  const long bn0 = (long)(swz % gx) * 256;

  char* lds = (char*)lds_dyn;

  // staging: chunk c = r*512 + w*64 + l -> row=c>>2, slot=c&3; LDS linear dest,
  // pre-swizzled global source chunk = slot ^ ((row>>1)&3) = (l&3) ^ ((l>>3)&3)
  int rowS[2];
  #pragma unroll
  for (int r = 0; r < 2; ++r) rowS[r] = r*128 + w*16 + (l >> 2);
  const int colS = ((l & 3) ^ ((l >> 3) & 3)) * 8;

  auto STAGE_A = [&](int t, int q){
    char* base = lds + q*32768;
    long k0 = (long)t * 32;
    #pragma unroll
    for (int r = 0; r < 2; ++r)
      gload_lds16(A + (bm0 + rowS[r])*(long)Kd + k0 + colS,
                  (u16*)(base + (r*512 + w*64)*16));
  };
  auto STAGE_B = [&](int t, int q){
    char* base = lds + q*32768 + 16384;
    long k0 = (long)t * 32;
    #pragma unroll
    for (int r = 0; r < 2; ++r)
      gload_lds16(Bm + (bn0 + rowS[r])*(long)Kd + k0 + colS,
                  (u16*)(base + (r*512 + w*64)*16));
  };

  // fragment read swizzle offset: slot = lq ^ ((lm>>1)&3)   (uniform 8 lanes/bank-quad)
  const unsigned soff = (unsigned)(lq ^ ((lm >> 1) & 3)) << 4;

  f32x4 acc[8][4];
  #pragma unroll
  for (int i = 0; i < 8; ++i)
    #pragma unroll
    for (int j = 0; j < 4; ++j) acc[i][j] = f32x4{0.f,0.f,0.f,0.f};

  const int NT = Kd >> 5;     // 32
  STAGE_A(0, 0); STAGE_B(0, 0);
  STAGE_A(1, 1); STAGE_B(1, 1);

  for (int t = 0; t < NT; ++t) {
    int q  = t % 3;
    int qn = (t + 2) % 3;
    int tn = (t + 2 < NT) ? (t + 2) : (NT - 1);

    asm volatile("s_waitcnt vmcnt(4)" ::: "memory");
    __builtin_amdgcn_s_barrier();
    asm volatile("" ::: "memory");

    const char* Ab = lds + q*32768;
    const char* Bb = Ab + 16384;

    bf16x8 bfr[4], afr[8];
    #pragma unroll
    for (int nf = 0; nf < 4; ++nf) {
      int rr = wn*64 + nf*16 + lm;
      bfr[nf] = *(const bf16x8*)(Bb + rr*64 + soff);
    }
    #pragma unroll
    for (int mf = 0; mf < 8; ++mf) {
      int rr = wm*128 + mf*16 + lm;
      afr[mf] = *(const bf16x8*)(Ab + rr*64 + soff);
    }
    STAGE_A(tn, qn);
    STAGE_B(tn, qn);

    __builtin_amdgcn_s_setprio(1);
    #pragma unroll
    for (int mf = 0; mf < 8; ++mf)
      #pragma unroll
      for (int nf = 0; nf < 4; ++nf)
        acc[mf][nf] = __builtin_amdgcn_mfma_f32_16x16x32_bf16(afr[mf], bfr[nf], acc[mf][nf], 0, 0, 0);
    __builtin_amdgcn_s_setprio(0);
  }

  // epilogue
  #pragma unroll
  for (int mf = 0; mf < 8; ++mf) {
    #pragma unroll
    for (int r = 0; r < 4; ++r) {
      long m = bm0 + wm*128 + mf*16 + lq*4 + r;
      #pragma unroll
      for (int nf = 0; nf < 4; ++nf) {
        long n = bn0 + wn*64 + nf*16 + lm;
        float val = acc[mf][nf][r];
        if (RESID) val += resid[m * N + n];
        if (OUTF32) Cf[m * N + n] = val;
        else        Cb[m * N + n] = f2bf(val);
      }
    }
  }
}

// ---------------- fallback bf16 NT GEMM (validated, 128^2) ----------------
template<int RESID, int OUTF32>
__global__ __launch_bounds__(256) void gemm_nt(
    const u16* __restrict__ A, const u16* __restrict__ Bm,
    u16* __restrict__ Cb, float* __restrict__ Cf, const float* __restrict__ resid,
    int M, int N, int Kd)
{
  __shared__ __align__(16) u16 Als[128 * 32];
  __shared__ __align__(16) u16 Bls[128 * 32];
  const int tid = threadIdx.x;
  const int w = tid >> 6, l = tid & 63;
  const int wr = w >> 1, wc = w & 1;
  const int lm = l & 15, lq = l >> 4;

  unsigned bid = blockIdx.y * gridDim.x + blockIdx.x;
  unsigned nwg = gridDim.x * gridDim.y;
  unsigned cpx = nwg >> 3;
  unsigned swz = (bid & 7) * cpx + (bid >> 3);
  const long bm0 = (long)(swz / gridDim.x) * 128;
  const long bn0 = (long)(swz % gridDim.x) * 128;

  f32x4 zero4 = {0.f, 0.f, 0.f, 0.f};
  f32x4 acc[4][4];
  #pragma unroll
  for (int i = 0; i < 4; i++)
    #pragma unroll
    for (int j = 0; j < 4; j++) acc[i][j] = zero4;

  for (int kk = 0; kk < Kd; kk += 32) {
    __syncthreads();
    #pragma unroll
    for (int it = 0; it < 2; it++) {
      int c = tid + it * 256;
      int r = c >> 2, kb = c & 3;
      const u16* ga = A  + (bm0 + r) * Kd + kk + kb * 8;
      const u16* gb = Bm + (bn0 + r) * Kd + kk + kb * 8;
      gload_lds16(ga, Als + (it * 256 + w * 64) * 8);
      gload_lds16(gb, Bls + (it * 256 + w * 64) * 8);
    }
    __syncthreads();
    bf16x8 af[4], bfr[4];
    #pragma unroll
    for (int f = 0; f < 4; f++)
      af[f] = *(const bf16x8*)(Als + (wr * 64 + f * 16 + lm) * 32 + lq * 8);
    #pragma unroll
    for (int f = 0; f < 4; f++)
      bfr[f] = *(const bf16x8*)(Bls + (wc * 64 + f * 16 + lm) * 32 + lq * 8);
    #pragma unroll
    for (int i = 0; i < 4; i++)
      #pragma unroll
      for (int j = 0; j < 4; j++)
        acc[i][j] = __builtin_amdgcn_mfma_f32_16x16x32_bf16(af[i], bfr[j], acc[i][j], 0, 0, 0);
  }

  #pragma unroll
  for (int i = 0; i < 4; i++) {
    #pragma unroll
    for (int r = 0; r < 4; r++) {
      long m = bm0 + wr * 64 + i * 16 + lq * 4 + r;
      #pragma unroll
      for (int j = 0; j < 4; j++) {
        long n = bn0 + wc * 64 + j * 16 + lm;
        float val = acc[i][j][r];
        if (RESID) val += resid[m * N + n];
        if (OUTF32) Cf[m * N + n] = val;
        else        Cb[m * N + n] = f2bf(val);
      }
    }
  }
}

// ---------------- postprocess ----------------
__global__ __launch_bounds__(64) void postproc(
    u16* __restrict__ kv, const float* __restrict__ bb, const float* __restrict__ bg,
    float* __restrict__ bArr, float* __restrict__ gArr)
{
  long row = blockIdx.x;
  int l = threadIdx.x;
  u16* rp = kv + row * NPAD;
  #pragma unroll
  for (int h = 0; h < 16; h++) {
    float xk = bf2f(rp[h * 64 + l]);
    float ss = xk * xk;
    #pragma unroll
    for (int m = 1; m < 64; m <<= 1) ss += __shfl_xor(ss, m, 64);
    float inv = 1.f / fmaxf(sqrtf(ss), 1e-12f);
    rp[h * 64 + l] = f2bf(xk * inv);
  }
  if (l < 32) {
    int hh = l & 15;
    float val = bf2f(rp[2048 + l]) + ((l < 16) ? bb[hh] : bg[hh]);
    float s = 1.f / (1.f + expf(-val));
    float* dst = (l < 16) ? bArr : gArr;
    long b = row >> 12;
    long t = row & 4095;
    dst[(b * H_ + hh) * (long)T_ + t] = s;
  }
}

// 64x64x64 NT matmul from LDS bf16 tiles (stride 72)
__device__ __forceinline__ void mm64(const u16* Ab, const u16* Bb,
                                     int lm, int lq, int wr, int wc, f32x4 acc[2][2])
{
  #pragma unroll
  for (int ks = 0; ks < 2; ++ks) {
    bf16x8 af[2], bfr[2];
    #pragma unroll
    for (int mi = 0; mi < 2; ++mi)
      af[mi] = *(const bf16x8*)(Ab + (wr*32 + mi*16 + lm)*72 + ks*32 + lq*8);
    #pragma unroll
    for (int ni = 0; ni < 2; ++ni)
      bfr[ni] = *(const bf16x8*)(Bb + (wc*32 + ni*16 + lm)*72 + ks*32 + lq*8);
    #pragma unroll
    for (int mi = 0; mi < 2; ++mi)
      #pragma unroll
      for (int ni = 0; ni < 2; ++ni)
        acc[mi][ni] = __builtin_amdgcn_mfma_f32_16x16x32_bf16(af[mi], bfr[ni], acc[mi][ni], 0, 0, 0);
  }
}

// ---------------- phase 1: per-chunk WY factors (blocked substitution) ----------------
__global__ __launch_bounds__(256) void chunk1(
    u16* __restrict__ kv, const float* __restrict__ bArr, const float* __restrict__ gArr,
    u16* __restrict__ p1buf, u16* __restrict__ r1buf)
{
  __shared__ __align__(16) u16 Kb[64*72];
  __shared__ __align__(16) u16 Utb[128*72];
  __shared__ __align__(16) u16 LpI[64*72];
  __shared__ __align__(16) u16 Abf[64*72];
  __shared__ __align__(16) float Ad[4*16*21];
  __shared__ float aLS[64], ainvLS[64], bLS[64], bapLS[64];
  __shared__ float aCsh;

  const int tid = threadIdx.x;
  const int w = tid >> 6, l = tid & 63;
  const int lm = l & 15, lq = l >> 4;
  const int wr = w >> 1, wc = w & 1;
  const int bh = blockIdx.x & 63, ch = blockIdx.x >> 6;
  const int b = bh >> 4, h = bh & 15;

  const u16* kbase = kv + ((long)b*T_ + ch*64)*NPAD + h*64;
  const u16* vbase = kbase + 1024;

  #pragma unroll
  for (int it = 0; it < 2; ++it) {
    int c = tid + it*256;
    int r = c >> 3, seg = (c & 7)*8;
    *(u16x8*)(Kb  + r*72 + seg) = *(const u16x8*)(kbase + (long)r*NPAD + seg);
    *(u16x8*)(Utb + r*72 + seg) = *(const u16x8*)(vbase + (long)r*NPAD + seg);
  }
  #pragma unroll
  for (int z = 0; z < 8; ++z) {
    int idx = tid + z*256;
    int rr = idx >> 5, wd = idx & 31;
    ((unsigned int*)(Utb + (64 + rr)*72))[wd] = 0u;
  }
  if (tid < 64) {
    float gv = gArr[(long)bh*T_ + ch*64 + tid];
    float bv = bArr[(long)bh*T_ + ch*64 + tid];
    float av = gv;
    #pragma unroll
    for (int off = 1; off < 64; off <<= 1) {
      float o = __shfl_up(av, off, 64);
      if (tid >= off) av *= o;
    }
    float ap = __shfl_up(av, 1, 64);
    if (tid == 0) ap = 1.f;
    float aC = __shfl(av, 63, 64);
    aLS[tid] = av; ainvLS[tid] = 1.f/av; bLS[tid] = bv; bapLS[tid] = bv*ap;
    if (tid == 0) aCsh = aC;
  }
  __syncthreads();

  f32x4 gf[2][2];
  #pragma unroll
  for (int mi = 0; mi < 2; ++mi)
    #pragma unroll
    for (int ni = 0; ni < 2; ++ni) gf[mi][ni] = f32x4{0.f,0.f,0.f,0.f};
  mm64(Kb, Kb, lm, lq, wr, wc, gf);

  float wv_[4][2][4];
  #pragma unroll
  for (int bi = 0; bi < 4; ++bi)
    #pragma unroll
    for (int ni = 0; ni < 2; ++ni) {
      int col = w*32 + ni*16 + lm;
      #pragma unroll
      for (int r = 0; r < 4; ++r) {
        int row = bi*16 + lq*4 + r;
        float sv = (col < 64) ? bf2f(Utb[row*72 + col]) : bf2f(Kb[row*72 + (col - 64)]);
        float coef = (col < 64) ? bLS[row] : bapLS[row];
        wv_[bi][ni][r] = coef * sv;
      }
    }

  #pragma unroll
  for (int mi = 0; mi < 2; ++mi)
    #pragma unroll
    for (int ni = 0; ni < 2; ++ni)
      #pragma unroll
      for (int r = 0; r < 4; ++r) {
        int row = wr*32 + mi*16 + lq*4 + r, col = wc*32 + ni*16 + lm;
        float gvl = gf[mi][ni][r];
        int rb = row >> 4, cb = col >> 4;
        Abf[row*72 + col] = f2bf((rb > cb) ? bapLS[row]*ainvLS[col]*gvl : 0.f);
        if (rb == cb)
          Ad[(rb*16 + (row & 15))*21 + (col & 15)] =
              ((col & 15) < (row & 15)) ? bapLS[row]*ainvLS[col]*gvl : 0.f;
        LpI[row*72 + col] = f2bf((col < row) ? aLS[row]*ainvLS[col]*gvl
                                             : ((col == row) ? 1.f : 0.f));
      }
  __syncthreads();

  #pragma unroll
  for (int bi = 0; bi < 4; ++bi) {
    if (bi > 0) {
      f32x4 corr[2] = { f32x4{0.f,0.f,0.f,0.f}, f32x4{0.f,0.f,0.f,0.f} };
      const int nks = (bi*16 + 31) >> 5;
      #pragma unroll
      for (int ks = 0; ks < 2; ++ks) {
        if (ks < nks) {
          bf16x8 afr = *(const bf16x8*)(Abf + (bi*16 + lm)*72 + ks*32 + lq*8);
          #pragma unroll
          for (int ni = 0; ni < 2; ++ni) {
            bf16x8 bfr = *(const bf16x8*)(Utb + (w*32 + ni*16 + lm)*72 + ks*32 + lq*8);
            corr[ni] = __builtin_amdgcn_mfma_f32_16x16x32_bf16(afr, bfr, corr[ni], 0, 0, 0);
          }
        }
      }
      #pragma unroll
      for (int ni = 0; ni < 2; ++ni)
        #pragma unroll
        for (int r = 0; r < 4; ++r) wv_[bi][ni][r] -= corr[ni][r];
    }
    #pragma unroll
    for (int i = 0; i < 16; ++i) {
      int src = ((i >> 2) << 4) | lm;
      float u0 = __shfl(wv_[bi][0][i & 3], src, 64);
      float u1 = __shfl(wv_[bi][1][i & 3], src, 64);
      #pragma unroll
      for (int r = 0; r < 4; ++r) {
        float ad = Ad[(bi*16 + lq*4 + r)*21 + i];
        wv_[bi][0][r] = fmaf(-ad, u0, wv_[bi][0][r]);
        wv_[bi][1][r] = fmaf(-ad, u1, wv_[bi][1][r]);
      }
    }
    #pragma unroll
    for (int ni = 0; ni < 2; ++ni) {
      int col = w*32 + ni*16 + lm;
      #pragma unroll
      for (int r = 0; r < 4; ++r)
        Utb[col*72 + bi*16 + lq*4 + r] = f2bf(wv_[bi][ni][r]);
    }
  }
  __syncthreads();

  const long pr_base = (((long)bh*64 + ch)*64);
  u16* qdst = kv + ((long)b*T_ + ch*64)*NPAD + h*64;
  u16* mdst = qdst + 1024;
  f32x4 acc[2][2];

  #pragma unroll
  for (int mi = 0; mi < 2; ++mi)
    #pragma unroll
    for (int ni = 0; ni < 2; ++ni) acc[mi][ni] = f32x4{0.f,0.f,0.f,0.f};
  mm64(Utb, LpI, lm, lq, wr, wc, acc);
  #pragma unroll
  for (int mi = 0; mi < 2; ++mi)
    #pragma unroll
    for (int ni = 0; ni < 2; ++ni)
      #pragma unroll
      for (int r = 0; r < 4; ++r) {
        int row = wr*32 + mi*16 + lq*4 + r, col = wc*32 + ni*16 + lm;
        p1buf[(pr_base + row)*64 + col] = f2bf(acc[mi][ni][r]);
      }

  #pragma unroll
  for (int mi = 0; mi < 2; ++mi)
    #pragma unroll
    for (int ni = 0; ni < 2; ++ni) acc[mi][ni] = f32x4{0.f,0.f,0.f,0.f};
  mm64(LpI, Utb + 64*72, lm, lq, wr, wc, acc);
  #pragma unroll
  for (int mi = 0; mi < 2; ++mi)
    #pragma unroll
    for (int ni = 0; ni < 2; ++ni)
      #pragma unroll
      for (int r = 0; r < 4; ++r) {
        int row = wr*32 + mi*16 + lq*4 + r, col = wc*32 + ni*16 + lm;
        float val = aLS[row]*bf2f(Kb[row*72 + col]) - acc[mi][ni][r];
        qdst[(long)row*NPAD + col] = f2bf(val);
      }

  {
    int kk_ = tid >> 2, sb = (tid & 3) * 16;
    float aC = aCsh;
    #pragma unroll
    for (int s5 = 0; s5 < 16; ++s5) {
      int s = sb + s5;
      Abf[kk_*72 + s] = f2bf(aC * ainvLS[s] * bf2f(Kb[s*72 + kk_]));
    }
  }
  __syncthreads();

  #pragma unroll
  for (int mi = 0; mi < 2; ++mi)
    #pragma unroll
    for (int ni = 0; ni < 2; ++ni) acc[mi][ni] = f32x4{0.f,0.f,0.f,0.f};
  mm64(Utb, Abf, lm, lq, wr, wc, acc);
  #pragma unroll
  for (int mi = 0; mi < 2; ++mi)
    #pragma unroll
    for (int ni = 0; ni < 2; ++ni)
      #pragma unroll
      for (int r = 0; r < 4; ++r) {
        int row = wr*32 + mi*16 + lq*4 + r, col = wc*32 + ni*16 + lm;
        r1buf[(pr_base + row)*64 + col] = f2bf(acc[mi][ni][r]);
      }

  #pragma unroll
  for (int mi = 0; mi < 2; ++mi)
    #pragma unroll
    for (int ni = 0; ni < 2; ++ni) acc[mi][ni] = f32x4{0.f,0.f,0.f,0.f};
  mm64(Abf, Utb + 64*72, lm, lq, wr, wc, acc);
  #pragma unroll
  for (int mi = 0; mi < 2; ++mi)
    #pragma unroll
    for (int ni = 0; ni < 2; ++ni)
      #pragma unroll
      for (int r = 0; r < 4; ++r) {
        int row = wr*32 + mi*16 + lq*4 + r, col = wc*32 + ni*16 + lm;
        float val = ((row == col) ? aCsh : 0.f) - acc[mi][ni][r];
        mdst[(long)row*NPAD + col] = f2bf(val);
      }
}

// ---------------- phase 2: sequential chunk recurrence ----------------
struct PF { u16x8 qf0, qf1, mf0, mf1; u16 p1[4]; u16 r1[4]; };

__global__ __launch_bounds__(256) void chunk2(
    const u16* __restrict__ kv, const u16* __restrict__ p1buf, const u16* __restrict__ r1buf,
    u16* __restrict__ outb)
{
  __shared__ __align__(16) u16 Zb[16*72];
  __shared__ __align__(16) u16 ot[64*24];
  const int tid = threadIdx.x;
  const int wcv = tid >> 6, l = tid & 63;
  const int lm = l & 15, lq = l >> 4;
  const int bh = blockIdx.x & 63, vg = blockIdx.x >> 6;
  const int b = bh >> 4, h = bh & 15;

  for (int idx = tid; idx < 16*72/2; idx += 256) ((unsigned int*)Zb)[idx] = 0u;

  const u16* pbase = p1buf + (long)bh*64*4096;
  const u16* rbase = r1buf + (long)bh*64*4096;

  auto LOADPF = [&](int ch, PF& p){
    long rq = ((long)b*T_ + ch*64 + wcv*16 + lm)*NPAD + h*64 + lq*8;
    p.qf0 = *(const u16x8*)(kv + rq);
    p.qf1 = *(const u16x8*)(kv + rq + 32);
    p.mf0 = *(const u16x8*)(kv + rq + 1024);
    p.mf1 = *(const u16x8*)(kv + rq + 1024 + 32);
    #pragma unroll
    for (int r = 0; r < 4; ++r) {
      long pv = (long)ch*4096 + (vg*16 + lq*4 + r)*64 + wcv*16 + lm;
      p.p1[r] = pbase[pv];
      p.r1[r] = rbase[pv];
    }
  };

  PF A, Bp;
  LOADPF(0, A);
  __syncthreads();

  auto STEP = [&](int ch, PF& use, PF& pre){
    bf16x8 za0 = *(const bf16x8*)(Zb + lm*72 + lq*8);
    bf16x8 za1 = *(const bf16x8*)(Zb + lm*72 + 32 + lq*8);
    if (ch < 63) LOADPF(ch + 1, pre);
    f32x4 accO = { bf2f(use.p1[0]), bf2f(use.p1[1]), bf2f(use.p1[2]), bf2f(use.p1[3]) };
    accO = __builtin_amdgcn_mfma_f32_16x16x32_bf16(za0, as_bf(use.qf0), accO, 0, 0, 0);
    accO = __builtin_amdgcn_mfma_f32_16x16x32_bf16(za1, as_bf(use.qf1), accO, 0, 0, 0);
    f32x4 accS = { bf2f(use.r1[0]), bf2f(use.r1[1]), bf2f(use.r1[2]), bf2f(use.r1[3]) };
    accS = __builtin_amdgcn_mfma_f32_16x16x32_bf16(za0, as_bf(use.mf0), accS, 0, 0, 0);
    accS = __builtin_amdgcn_mfma_f32_16x16x32_bf16(za1, as_bf(use.mf1), accS, 0, 0, 0);
    #pragma unroll
    for (int r = 0; r < 4; ++r) ot[(wcv*16 + lm)*24 + lq*4 + r] = f2bf(accO[r]);
    __syncthreads();
    #pragma unroll
    for (int r = 0; r < 4; ++r) Zb[(lq*4 + r)*72 + wcv*16 + lm] = f2bf(accS[r]);
    {
      int i2 = tid >> 2, q4 = tid & 3;
      u16x4 ov = *(const u16x4*)(ot + i2*24 + q4*4);
      *(u16x4*)(outb + ((long)b*T_ + ch*64 + i2)*D_ + h*64 + vg*16 + q4*4) = ov;
    }
    __syncthreads();
  };

  for (int c2 = 0; c2 < 32; ++c2) {
    STEP(2*c2,     A, Bp);
    STEP(2*c2 + 1, Bp, A);
  }
}

extern "C" void kernel_launch(void* const* d_in, const int* in_sizes, int n_in,
                              void* d_out, int out_size, void* d_ws, size_t ws_size,
                              hipStream_t stream) {
  const float* x     = (const float*)d_in[0];
  const float* normw = (const float*)d_in[1];
  const float* Wk    = (const float*)d_in[2];
  const float* Wv    = (const float*)d_in[3];
  const float* Wo    = (const float*)d_in[4];
  const float* Wb    = (const float*)d_in[5];
  const float* bb    = (const float*)d_in[6];
  const float* Wg    = (const float*)d_in[7];
  const float* bg    = (const float*)d_in[8];
  float* y = (float*)d_out;

  char* ws = (char*)d_ws;
  u16* xn    = (u16*)ws;   ws += (long)ROWS * D_ * 2;      // 33.5 MB (reused as P1^T)
  u16* Wcomb = (u16*)ws;   ws += (long)NPAD * D_ * 2;      // 4.7 MB
  u16* Wob   = (u16*)ws;   ws += (long)D_ * D_ * 2;        // 2 MB
  u16* kvb   = (u16*)ws;   ws += (long)ROWS * NPAD * 2;    // 75.5 MB (k,v -> Q,M in place)
  float* bA  = (float*)ws; ws += (long)B_ * H_ * T_ * 4;
  float* gA  = (float*)ws; ws += (long)B_ * H_ * T_ * 4;
  u16* outb  = (u16*)ws;   ws += (long)ROWS * D_ * 2;
  u16* r1b   = (u16*)ws;   ws += (long)64 * 64 * 4096 * 2; // R1^T

  const int LDSB = 3 * 32768;
  bool big = true;
  if (hipFuncSetAttribute(reinterpret_cast<const void*>(gemm256<0,0>),
        hipFuncAttributeMaxDynamicSharedMemorySize, LDSB) != hipSuccess) big = false;
  if (hipFuncSetAttribute(reinterpret_cast<const void*>(gemm256<1,1>),
        hipFuncAttributeMaxDynamicSharedMemorySize, LDSB) != hipSuccess) big = false;

  const long prep_total = (long)NPAD * D_ + (long)D_ * D_;
  prep_w<<<dim3((unsigned)(prep_total / 256)), dim3(256), 0, stream>>>(
      Wk, Wv, Wb, Wg, Wo, Wcomb, Wob);
  rmsnorm_k<<<dim3(ROWS), dim3(256), 0, stream>>>(x, normw, xn);
  if (big)
    gemm256<0, 0><<<dim3(NPAD / 256, ROWS / 256), dim3(512), LDSB, stream>>>(
        xn, Wcomb, kvb, (float*)nullptr, (const float*)nullptr, ROWS, NPAD, D_);
  else
    gemm_nt<0, 0><<<dim3(NPAD / 128, ROWS / 128), dim3(256), 0, stream>>>(
        xn, Wcomb, kvb, (float*)nullptr, (const float*)nullptr, ROWS, NPAD, D_);
  postproc<<<dim3(ROWS), dim3(64), 0, stream>>>(kvb, bb, bg, bA, gA);
  chunk1<<<dim3(4096), dim3(256), 0, stream>>>(kvb, bA, gA, xn, r1b);
  chunk2<<<dim3(256), dim3(256), 0, stream>>>(kvb, xn, r1b, outb);
  if (big)
    gemm256<1, 1><<<dim3(D_ / 256, ROWS / 256), dim3(512), LDSB, stream>>>(
        outb, Wob, (u16*)nullptr, y, x, ROWS, D_, D_);
  else
    gemm_nt<1, 1><<<dim3(D_ / 128, ROWS / 128), dim3(256), 0, stream>>>(
        outb, Wob, (u16*)nullptr, y, x, ROWS, D_, D_);
}

// Round 6
// 321.014 us; speedup vs baseline: 3.7709x; 1.0862x over previous
//
#include <hip/hip_runtime.h>
#include <stdint.h>

#define B_ 4
#define T_ 4096
#define D_ 1024
#define H_ 16
#define NPAD 2304            // 1024 k + 1024 v + 16 beta + 16 g + 224 zero-pad (multiple of 256)
#define ROWS (B_*T_)         // 16384

typedef __bf16 bf16x8 __attribute__((ext_vector_type(8)));
typedef float  f32x4  __attribute__((ext_vector_type(4)));
typedef unsigned short u16;
typedef u16 u16x8 __attribute__((ext_vector_type(8)));
typedef u16 u16x4 __attribute__((ext_vector_type(4)));

__device__ __forceinline__ float bf2f(u16 u){
  union { unsigned int i; float f; } x; x.i = ((unsigned int)u) << 16; return x.f;
}
__device__ __forceinline__ u16 f2bf(float f){
  union { float f; unsigned int i; } x; x.f = f;
  unsigned int r = x.i + 0x7fffu + ((x.i >> 16) & 1u);
  return (u16)(r >> 16);
}
__device__ __forceinline__ bf16x8 as_bf(u16x8 v){ union{u16x8 u; bf16x8 b;} x; x.u = v; return x.b; }

__device__ __forceinline__ void gload_lds16(const u16* g, u16* l){
  __builtin_amdgcn_global_load_lds(
      (const __attribute__((address_space(1))) unsigned int*)g,
      (__attribute__((address_space(3))) unsigned int*)l, 16, 0, 0);
}

// ---------------- weight prep ----------------
__global__ __launch_bounds__(256) void prep_w(
    const float* __restrict__ Wk, const float* __restrict__ Wv,
    const float* __restrict__ Wb, const float* __restrict__ Wg,
    const float* __restrict__ Wo, u16* __restrict__ Wcomb, u16* __restrict__ Wob)
{
  long i = (long)blockIdx.x * 256 + threadIdx.x;
  const long tot1 = (long)NPAD * D_;
  if (i < tot1) {
    long n = i >> 10, d = i & 1023;
    float v;
    if      (n < 1024) v = Wk[n * 1024 + d];
    else if (n < 2048) v = Wv[(n - 1024) * 1024 + d];
    else if (n < 2064) v = Wb[(n - 2048) * 1024 + d];
    else if (n < 2080) v = Wg[(n - 2064) * 1024 + d];
    else               v = 0.f;
    Wcomb[i] = f2bf(v);
  } else {
    long j = i - tot1;
    Wob[j] = f2bf(Wo[j]);
  }
}

// ---------------- RMSNorm ----------------
__global__ __launch_bounds__(256) void rmsnorm_k(
    const float* __restrict__ x, const float* __restrict__ w, u16* __restrict__ xn)
{
  long row = blockIdx.x;
  int tid = threadIdx.x;
  int l = tid & 63, wv = tid >> 6;
  f32x4 v = ((const f32x4*)(x + row * D_))[tid];
  float ss = v[0]*v[0] + v[1]*v[1] + v[2]*v[2] + v[3]*v[3];
  #pragma unroll
  for (int m = 1; m < 64; m <<= 1) ss += __shfl_xor(ss, m, 64);
  __shared__ float red[4];
  if (l == 0) red[wv] = ss;
  __syncthreads();
  float tot = red[0] + red[1] + red[2] + red[3];
  float inv = rsqrtf(tot * (1.f / (float)D_) + 1e-6f);
  f32x4 wv4 = ((const f32x4*)w)[tid];
  u16x4 o;
  o[0] = f2bf(v[0] * inv * wv4[0]);
  o[1] = f2bf(v[1] * inv * wv4[1]);
  o[2] = f2bf(v[2] * inv * wv4[2]);
  o[3] = f2bf(v[3] * inv * wv4[3]);
  ((u16x4*)(xn + row * D_))[tid] = o;
}

// ---------------- 256x256 deep-pipelined bf16 NT GEMM ----------------
extern __shared__ f32x4 lds_dyn[];

template<int RESID, int OUTF32>
__global__ __launch_bounds__(512, 2) void gemm256(
    const u16* __restrict__ A, const u16* __restrict__ Bm,
    u16* __restrict__ Cb, float* __restrict__ Cf, const float* __restrict__ resid,
    int M, int N, int Kd)
{
  const int tid = threadIdx.x;
  const int w = tid >> 6, l = tid & 63;
  const int lm = l & 15, lq = l >> 4;
  const int wm = w >> 2, wn = w & 3;

  unsigned gx = gridDim.x;
  unsigned bid = blockIdx.y * gx + blockIdx.x;
  unsigned nwg = gx * gridDim.y;
  unsigned cpx = nwg >> 3;
  unsigned swz = (bid & 7) * cpx + (bid >> 3);
  const long bm0 = (long)(swz / gx) * 256;
  const long bn0 = (long)(swz % gx) * 256;

  char* lds = (char*)lds_dyn;

  int rowS[2];
  #pragma unroll
  for (int r = 0; r < 2; ++r) rowS[r] = r*128 + w*16 + (l >> 2);
  const int colS = ((l & 3) ^ ((l >> 3) & 3)) * 8;

  auto STAGE_A = [&](int t, int q){
    char* base = lds + q*32768;
    long k0 = (long)t * 32;
    #pragma unroll
    for (int r = 0; r < 2; ++r)
      gload_lds16(A + (bm0 + rowS[r])*(long)Kd + k0 + colS,
                  (u16*)(base + (r*512 + w*64)*16));
  };
  auto STAGE_B = [&](int t, int q){
    char* base = lds + q*32768 + 16384;
    long k0 = (long)t * 32;
    #pragma unroll
    for (int r = 0; r < 2; ++r)
      gload_lds16(Bm + (bn0 + rowS[r])*(long)Kd + k0 + colS,
                  (u16*)(base + (r*512 + w*64)*16));
  };

  const unsigned soff = (unsigned)(lq ^ ((lm >> 1) & 3)) << 4;

  f32x4 acc[8][4];
  #pragma unroll
  for (int i = 0; i < 8; ++i)
    #pragma unroll
    for (int j = 0; j < 4; ++j) acc[i][j] = f32x4{0.f,0.f,0.f,0.f};

  const int NT = Kd >> 5;     // 32
  STAGE_A(0, 0); STAGE_B(0, 0);
  STAGE_A(1, 1); STAGE_B(1, 1);

  for (int t = 0; t < NT; ++t) {
    int q  = t % 3;
    int qn = (t + 2) % 3;
    int tn = (t + 2 < NT) ? (t + 2) : (NT - 1);

    asm volatile("s_waitcnt vmcnt(4)" ::: "memory");
    __builtin_amdgcn_s_barrier();
    asm volatile("" ::: "memory");

    const char* Ab = lds + q*32768;
    const char* Bb = Ab + 16384;

    bf16x8 bfr[4], afr[8];
    #pragma unroll
    for (int nf = 0; nf < 4; ++nf) {
      int rr = wn*64 + nf*16 + lm;
      bfr[nf] = *(const bf16x8*)(Bb + rr*64 + soff);
    }
    #pragma unroll
    for (int mf = 0; mf < 8; ++mf) {
      int rr = wm*128 + mf*16 + lm;
      afr[mf] = *(const bf16x8*)(Ab + rr*64 + soff);
    }
    STAGE_A(tn, qn);
    STAGE_B(tn, qn);

    __builtin_amdgcn_s_setprio(1);
    #pragma unroll
    for (int mf = 0; mf < 8; ++mf)
      #pragma unroll
      for (int nf = 0; nf < 4; ++nf)
        acc[mf][nf] = __builtin_amdgcn_mfma_f32_16x16x32_bf16(afr[mf], bfr[nf], acc[mf][nf], 0, 0, 0);
    __builtin_amdgcn_s_setprio(0);
  }

  #pragma unroll
  for (int mf = 0; mf < 8; ++mf) {
    #pragma unroll
    for (int r = 0; r < 4; ++r) {
      long m = bm0 + wm*128 + mf*16 + lq*4 + r;
      #pragma unroll
      for (int nf = 0; nf < 4; ++nf) {
        long n = bn0 + wn*64 + nf*16 + lm;
        float val = acc[mf][nf][r];
        if (RESID) val += resid[m * N + n];
        if (OUTF32) Cf[m * N + n] = val;
        else        Cb[m * N + n] = f2bf(val);
      }
    }
  }
}

// ---------------- fallback bf16 NT GEMM (validated, 128^2) ----------------
template<int RESID, int OUTF32>
__global__ __launch_bounds__(256) void gemm_nt(
    const u16* __restrict__ A, const u16* __restrict__ Bm,
    u16* __restrict__ Cb, float* __restrict__ Cf, const float* __restrict__ resid,
    int M, int N, int Kd)
{
  __shared__ __align__(16) u16 Als[128 * 32];
  __shared__ __align__(16) u16 Bls[128 * 32];
  const int tid = threadIdx.x;
  const int w = tid >> 6, l = tid & 63;
  const int wr = w >> 1, wc = w & 1;
  const int lm = l & 15, lq = l >> 4;

  unsigned bid = blockIdx.y * gridDim.x + blockIdx.x;
  unsigned nwg = gridDim.x * gridDim.y;
  unsigned cpx = nwg >> 3;
  unsigned swz = (bid & 7) * cpx + (bid >> 3);
  const long bm0 = (long)(swz / gridDim.x) * 128;
  const long bn0 = (long)(swz % gridDim.x) * 128;

  f32x4 zero4 = {0.f, 0.f, 0.f, 0.f};
  f32x4 acc[4][4];
  #pragma unroll
  for (int i = 0; i < 4; i++)
    #pragma unroll
    for (int j = 0; j < 4; j++) acc[i][j] = zero4;

  for (int kk = 0; kk < Kd; kk += 32) {
    __syncthreads();
    #pragma unroll
    for (int it = 0; it < 2; it++) {
      int c = tid + it * 256;
      int r = c >> 2, kb = c & 3;
      const u16* ga = A  + (bm0 + r) * Kd + kk + kb * 8;
      const u16* gb = Bm + (bn0 + r) * Kd + kk + kb * 8;
      gload_lds16(ga, Als + (it * 256 + w * 64) * 8);
      gload_lds16(gb, Bls + (it * 256 + w * 64) * 8);
    }
    __syncthreads();
    bf16x8 af[4], bfr[4];
    #pragma unroll
    for (int f = 0; f < 4; f++)
      af[f] = *(const bf16x8*)(Als + (wr * 64 + f * 16 + lm) * 32 + lq * 8);
    #pragma unroll
    for (int f = 0; f < 4; f++)
      bfr[f] = *(const bf16x8*)(Bls + (wc * 64 + f * 16 + lm) * 32 + lq * 8);
    #pragma unroll
    for (int i = 0; i < 4; i++)
      #pragma unroll
      for (int j = 0; j < 4; j++)
        acc[i][j] = __builtin_amdgcn_mfma_f32_16x16x32_bf16(af[i], bfr[j], acc[i][j], 0, 0, 0);
  }

  #pragma unroll
  for (int i = 0; i < 4; i++) {
    #pragma unroll
    for (int r = 0; r < 4; r++) {
      long m = bm0 + wr * 64 + i * 16 + lq * 4 + r;
      #pragma unroll
      for (int j = 0; j < 4; j++) {
        long n = bn0 + wc * 64 + j * 16 + lm;
        float val = acc[i][j][r];
        if (RESID) val += resid[m * N + n];
        if (OUTF32) Cf[m * N + n] = val;
        else        Cb[m * N + n] = f2bf(val);
      }
    }
  }
}

// ---------------- sigmoid for beta/g (postproc replaced; k-norm folded into chunk1) ----------------
__global__ __launch_bounds__(256) void sigmoid_bg(
    const u16* __restrict__ kv, const float* __restrict__ bb, const float* __restrict__ bg,
    float* __restrict__ bArr, float* __restrict__ gArr)
{
  int idx = blockIdx.x * 256 + threadIdx.x;   // ROWS*32 total
  int row = idx >> 5, c = idx & 31;
  int h = c & 15;
  float val = bf2f(kv[(long)row * NPAD + 2048 + c]) + ((c < 16) ? bb[h] : bg[h]);
  float s = 1.f / (1.f + expf(-val));
  long b = row >> 12, t = row & 4095;
  float* dst = (c < 16) ? bArr : gArr;
  dst[(b * H_ + h) * (long)T_ + t] = s;
}

// 64x64x64 NT matmul from LDS bf16 tiles (stride 72)
__device__ __forceinline__ void mm64(const u16* Ab, const u16* Bb,
                                     int lm, int lq, int wr, int wc, f32x4 acc[2][2])
{
  #pragma unroll
  for (int ks = 0; ks < 2; ++ks) {
    bf16x8 af[2], bfr[2];
    #pragma unroll
    for (int mi = 0; mi < 2; ++mi)
      af[mi] = *(const bf16x8*)(Ab + (wr*32 + mi*16 + lm)*72 + ks*32 + lq*8);
    #pragma unroll
    for (int ni = 0; ni < 2; ++ni)
      bfr[ni] = *(const bf16x8*)(Bb + (wc*32 + ni*16 + lm)*72 + ks*32 + lq*8);
    #pragma unroll
    for (int mi = 0; mi < 2; ++mi)
      #pragma unroll
      for (int ni = 0; ni < 2; ++ni)
        acc[mi][ni] = __builtin_amdgcn_mfma_f32_16x16x32_bf16(af[mi], bfr[ni], acc[mi][ni], 0, 0, 0);
  }
}

// ---------------- phase 1: per-chunk WY factors ----------------
// k-normalization folded in: n_s = rsqrt(diag(K K^T)); aLS/ainvLS/bapLS scaled by n.
// Diag-block A kept in bf16 regs (preloaded u16x8, static idx) -> no in-loop LDS reads.
__global__ __launch_bounds__(256) void chunk1(
    u16* __restrict__ kv, const float* __restrict__ bArr, const float* __restrict__ gArr,
    u16* __restrict__ p1buf, u16* __restrict__ r1buf)
{
  __shared__ __align__(16) u16 Kb[64*72];      // raw K chunk [s][k]
  __shared__ __align__(16) u16 Utb[128*72];    // V staged -> U^T
  __shared__ __align__(16) u16 LpI[64*72];
  __shared__ __align__(16) u16 Abf[64*72];     // off-diag A (diag zero) -> later Ktb
  __shared__ __align__(16) u16 Adb[4*16*24];   // bf16 diag-block A, stride 24
  __shared__ float nrm2LS[64];
  __shared__ float aLS[64], ainvLS[64], bLS[64], bapLS[64];
  __shared__ float aCsh;

  const int tid = threadIdx.x;
  const int w = tid >> 6, l = tid & 63;
  const int lm = l & 15, lq = l >> 4;
  const int wr = w >> 1, wc = w & 1;
  const int bh = blockIdx.x & 63, ch = blockIdx.x >> 6;
  const int b = bh >> 4, h = bh & 15;

  const u16* kbase = kv + ((long)b*T_ + ch*64)*NPAD + h*64;
  const u16* vbase = kbase + 1024;

  #pragma unroll
  for (int it = 0; it < 2; ++it) {
    int c = tid + it*256;
    int r = c >> 3, seg = (c & 7)*8;
    *(u16x8*)(Kb  + r*72 + seg) = *(const u16x8*)(kbase + (long)r*NPAD + seg);
    *(u16x8*)(Utb + r*72 + seg) = *(const u16x8*)(vbase + (long)r*NPAD + seg);
  }
  #pragma unroll
  for (int z = 0; z < 8; ++z) {
    int idx = tid + z*256;
    int rr = idx >> 5, wd = idx & 31;
    ((unsigned int*)(Utb + (64 + rr)*72))[wd] = 0u;
  }
  if (tid < 64) {
    float gv = gArr[(long)bh*T_ + ch*64 + tid];
    float bv = bArr[(long)bh*T_ + ch*64 + tid];
    float av = gv;
    #pragma unroll
    for (int off = 1; off < 64; off <<= 1) {
      float o = __shfl_up(av, off, 64);
      if (tid >= off) av *= o;
    }
    float ap = __shfl_up(av, 1, 64);
    if (tid == 0) ap = 1.f;
    float aC = __shfl(av, 63, 64);
    aLS[tid] = av; ainvLS[tid] = 1.f/av; bLS[tid] = bv; bapLS[tid] = bv*ap;
    if (tid == 0) aCsh = aC;
  }
  __syncthreads();   // bar1

  // G = K K^T (raw bf16 k, f32 accum)
  f32x4 gf[2][2];
  #pragma unroll
  for (int mi = 0; mi < 2; ++mi)
    #pragma unroll
    for (int ni = 0; ni < 2; ++ni) gf[mi][ni] = f32x4{0.f,0.f,0.f,0.f};
  mm64(Kb, Kb, lm, lq, wr, wc, gf);

  // extract diag -> norms
  #pragma unroll
  for (int mi = 0; mi < 2; ++mi)
    #pragma unroll
    for (int ni = 0; ni < 2; ++ni)
      #pragma unroll
      for (int r = 0; r < 4; ++r) {
        int row = wr*32 + mi*16 + lq*4 + r, col = wc*32 + ni*16 + lm;
        if (row == col) nrm2LS[row] = gf[mi][ni][r];
      }
  __syncthreads();   // bar1.5
  if (tid < 64) {
    float nv = 1.f / fmaxf(sqrtf(nrm2LS[tid]), 1e-12f);
    aLS[tid] *= nv; ainvLS[tid] *= nv; bapLS[tid] *= nv;
  }
  __syncthreads();   // bar1.75

  // W-init (V raw; K raw with bapLS now carrying n)
  float wv_[4][2][4];
  #pragma unroll
  for (int bi = 0; bi < 4; ++bi)
    #pragma unroll
    for (int ni = 0; ni < 2; ++ni) {
      int col = w*32 + ni*16 + lm;
      #pragma unroll
      for (int r = 0; r < 4; ++r) {
        int row = bi*16 + lq*4 + r;
        float sv = (col < 64) ? bf2f(Utb[row*72 + col]) : bf2f(Kb[row*72 + (col - 64)]);
        float coef = (col < 64) ? bLS[row] : bapLS[row];
        wv_[bi][ni][r] = coef * sv;
      }
    }

  // Abf (off-diag), Adb (diag bf16), LpI — coefficients carry n on both sides
  #pragma unroll
  for (int mi = 0; mi < 2; ++mi)
    #pragma unroll
    for (int ni = 0; ni < 2; ++ni)
      #pragma unroll
      for (int r = 0; r < 4; ++r) {
        int row = wr*32 + mi*16 + lq*4 + r, col = wc*32 + ni*16 + lm;
        float gvl = gf[mi][ni][r];
        int rb = row >> 4, cb = col >> 4;
        Abf[row*72 + col] = f2bf((rb > cb) ? bapLS[row]*ainvLS[col]*gvl : 0.f);
        if (rb == cb)
          Adb[rb*384 + (row & 15)*24 + (col & 15)] =
              f2bf(((col & 15) < (row & 15)) ? bapLS[row]*ainvLS[col]*gvl : 0.f);
        LpI[row*72 + col] = f2bf((col < row) ? aLS[row]*ainvLS[col]*gvl
                                             : ((col == row) ? 1.f : 0.f));
      }
  __syncthreads();   // bar2

  // blocked forward substitution
  #pragma unroll
  for (int bi = 0; bi < 4; ++bi) {
    if (bi > 0) {
      f32x4 corr[2] = { f32x4{0.f,0.f,0.f,0.f}, f32x4{0.f,0.f,0.f,0.f} };
      const int nks = (bi*16 + 31) >> 5;
      #pragma unroll
      for (int ks = 0; ks < 2; ++ks) {
        if (ks < nks) {
          bf16x8 afr = *(const bf16x8*)(Abf + (bi*16 + lm)*72 + ks*32 + lq*8);
          #pragma unroll
          for (int ni = 0; ni < 2; ++ni) {
            bf16x8 bfr = *(const bf16x8*)(Utb + (w*32 + ni*16 + lm)*72 + ks*32 + lq*8);
            corr[ni] = __builtin_amdgcn_mfma_f32_16x16x32_bf16(afr, bfr, corr[ni], 0, 0, 0);
          }
        }
      }
      #pragma unroll
      for (int ni = 0; ni < 2; ++ni)
        #pragma unroll
        for (int r = 0; r < 4; ++r) wv_[bi][ni][r] -= corr[ni][r];
    }
    // preload diag-block A rows (bf16, static idx)
    u16x8 ad0[4], ad1[4];
    #pragma unroll
    for (int r = 0; r < 4; ++r) {
      ad0[r] = *(const u16x8*)(Adb + bi*384 + (lq*4 + r)*24);
      ad1[r] = *(const u16x8*)(Adb + bi*384 + (lq*4 + r)*24 + 8);
    }
    #pragma unroll
    for (int i = 0; i < 16; ++i) {
      int src = ((i >> 2) << 4) | lm;
      float u0 = __shfl(wv_[bi][0][i & 3], src, 64);
      float u1 = __shfl(wv_[bi][1][i & 3], src, 64);
      #pragma unroll
      for (int r = 0; r < 4; ++r) {
        float ad = bf2f((i < 8) ? ad0[r][i] : ad1[r][i - 8]);
        wv_[bi][0][r] = fmaf(-ad, u0, wv_[bi][0][r]);
        wv_[bi][1][r] = fmaf(-ad, u1, wv_[bi][1][r]);
      }
    }
    #pragma unroll
    for (int ni = 0; ni < 2; ++ni) {
      int col = w*32 + ni*16 + lm;
      #pragma unroll
      for (int r = 0; r < 4; ++r)
        Utb[col*72 + bi*16 + lq*4 + r] = f2bf(wv_[bi][ni][r]);
    }
  }
  __syncthreads();   // bar3

  const long pr_base = (((long)bh*64 + ch)*64);
  u16* qdst = kv + ((long)b*T_ + ch*64)*NPAD + h*64;
  u16* mdst = qdst + 1024;
  f32x4 acc[2][2];

  // P1^T
  #pragma unroll
  for (int mi = 0; mi < 2; ++mi)
    #pragma unroll
    for (int ni = 0; ni < 2; ++ni) acc[mi][ni] = f32x4{0.f,0.f,0.f,0.f};
  mm64(Utb, LpI, lm, lq, wr, wc, acc);
  #pragma unroll
  for (int mi = 0; mi < 2; ++mi)
    #pragma unroll
    for (int ni = 0; ni < 2; ++ni)
      #pragma unroll
      for (int r = 0; r < 4; ++r) {
        int row = wr*32 + mi*16 + lq*4 + r, col = wc*32 + ni*16 + lm;
        p1buf[(pr_base + row)*64 + col] = f2bf(acc[mi][ni][r]);
      }

  // Q
  #pragma unroll
  for (int mi = 0; mi < 2; ++mi)
    #pragma unroll
    for (int ni = 0; ni < 2; ++ni) acc[mi][ni] = f32x4{0.f,0.f,0.f,0.f};
  mm64(LpI, Utb + 64*72, lm, lq, wr, wc, acc);
  #pragma unroll
  for (int mi = 0; mi < 2; ++mi)
    #pragma unroll
    for (int ni = 0; ni < 2; ++ni)
      #pragma unroll
      for (int r = 0; r < 4; ++r) {
        int row = wr*32 + mi*16 + lq*4 + r, col = wc*32 + ni*16 + lm;
        float val = aLS[row]*bf2f(Kb[row*72 + col]) - acc[mi][ni][r];
        qdst[(long)row*NPAD + col] = f2bf(val);
      }

  // Ktb (into Abf): Ktb[k][s] = aC * ainvLS[s] * K_raw[s][k]   (ainvLS carries n)
  {
    int s = tid & 63, kk0 = (tid >> 6) * 16;
    float coef = aCsh * ainvLS[s];
    #pragma unroll
    for (int j = 0; j < 16; ++j)
      Abf[(kk0 + j)*72 + s] = f2bf(coef * bf2f(Kb[s*72 + kk0 + j]));
  }
  __syncthreads();   // bar4

  // R1^T
  #pragma unroll
  for (int mi = 0; mi < 2; ++mi)
    #pragma unroll
    for (int ni = 0; ni < 2; ++ni) acc[mi][ni] = f32x4{0.f,0.f,0.f,0.f};
  mm64(Utb, Abf, lm, lq, wr, wc, acc);
  #pragma unroll
  for (int mi = 0; mi < 2; ++mi)
    #pragma unroll
    for (int ni = 0; ni < 2; ++ni)
      #pragma unroll
      for (int r = 0; r < 4; ++r) {
        int row = wr*32 + mi*16 + lq*4 + r, col = wc*32 + ni*16 + lm;
        r1buf[(pr_base + row)*64 + col] = f2bf(acc[mi][ni][r]);
      }

  // M
  #pragma unroll
  for (int mi = 0; mi < 2; ++mi)
    #pragma unroll
    for (int ni = 0; ni < 2; ++ni) acc[mi][ni] = f32x4{0.f,0.f,0.f,0.f};
  mm64(Abf, Utb + 64*72, lm, lq, wr, wc, acc);
  #pragma unroll
  for (int mi = 0; mi < 2; ++mi)
    #pragma unroll
    for (int ni = 0; ni < 2; ++ni)
      #pragma unroll
      for (int r = 0; r < 4; ++r) {
        int row = wr*32 + mi*16 + lq*4 + r, col = wc*32 + ni*16 + lm;
        float val = ((row == col) ? aCsh : 0.f) - acc[mi][ni][r];
        mdst[(long)row*NPAD + col] = f2bf(val);
      }
}

// ---------------- phase 2: sequential chunk recurrence ----------------
struct PF { u16x8 qf0, qf1, mf0, mf1; u16 p1[4]; u16 r1[4]; };

__global__ __launch_bounds__(256) void chunk2(
    const u16* __restrict__ kv, const u16* __restrict__ p1buf, const u16* __restrict__ r1buf,
    u16* __restrict__ outb)
{
  __shared__ __align__(16) u16 Zb[16*72];
  __shared__ __align__(16) u16 ot[64*24];
  const int tid = threadIdx.x;
  const int wcv = tid >> 6, l = tid & 63;
  const int lm = l & 15, lq = l >> 4;
  const int bh = blockIdx.x & 63, vg = blockIdx.x >> 6;
  const int b = bh >> 4, h = bh & 15;

  for (int idx = tid; idx < 16*72/2; idx += 256) ((unsigned int*)Zb)[idx] = 0u;

  const u16* pbase = p1buf + (long)bh*64*4096;
  const u16* rbase = r1buf + (long)bh*64*4096;

  auto LOADPF = [&](int ch, PF& p){
    long rq = ((long)b*T_ + ch*64 + wcv*16 + lm)*NPAD + h*64 + lq*8;
    p.qf0 = *(const u16x8*)(kv + rq);
    p.qf1 = *(const u16x8*)(kv + rq + 32);
    p.mf0 = *(const u16x8*)(kv + rq + 1024);
    p.mf1 = *(const u16x8*)(kv + rq + 1024 + 32);
    #pragma unroll
    for (int r = 0; r < 4; ++r) {
      long pv = (long)ch*4096 + (vg*16 + lq*4 + r)*64 + wcv*16 + lm;
      p.p1[r] = pbase[pv];
      p.r1[r] = rbase[pv];
    }
  };

  PF A, Bp;
  LOADPF(0, A);
  __syncthreads();

  auto STEP = [&](int ch, PF& use, PF& pre){
    bf16x8 za0 = *(const bf16x8*)(Zb + lm*72 + lq*8);
    bf16x8 za1 = *(const bf16x8*)(Zb + lm*72 + 32 + lq*8);
    if (ch < 63) LOADPF(ch + 1, pre);
    f32x4 accO = { bf2f(use.p1[0]), bf2f(use.p1[1]), bf2f(use.p1[2]), bf2f(use.p1[3]) };
    accO = __builtin_amdgcn_mfma_f32_16x16x32_bf16(za0, as_bf(use.qf0), accO, 0, 0, 0);
    accO = __builtin_amdgcn_mfma_f32_16x16x32_bf16(za1, as_bf(use.qf1), accO, 0, 0, 0);
    f32x4 accS = { bf2f(use.r1[0]), bf2f(use.r1[1]), bf2f(use.r1[2]), bf2f(use.r1[3]) };
    accS = __builtin_amdgcn_mfma_f32_16x16x32_bf16(za0, as_bf(use.mf0), accS, 0, 0, 0);
    accS = __builtin_amdgcn_mfma_f32_16x16x32_bf16(za1, as_bf(use.mf1), accS, 0, 0, 0);
    #pragma unroll
    for (int r = 0; r < 4; ++r) ot[(wcv*16 + lm)*24 + lq*4 + r] = f2bf(accO[r]);
    __syncthreads();
    #pragma unroll
    for (int r = 0; r < 4; ++r) Zb[(lq*4 + r)*72 + wcv*16 + lm] = f2bf(accS[r]);
    {
      int i2 = tid >> 2, q4 = tid & 3;
      u16x4 ov = *(const u16x4*)(ot + i2*24 + q4*4);
      *(u16x4*)(outb + ((long)b*T_ + ch*64 + i2)*D_ + h*64 + vg*16 + q4*4) = ov;
    }
    __syncthreads();
  };

  for (int c2 = 0; c2 < 32; ++c2) {
    STEP(2*c2,     A, Bp);
    STEP(2*c2 + 1, Bp, A);
  }
}

extern "C" void kernel_launch(void* const* d_in, const int* in_sizes, int n_in,
                              void* d_out, int out_size, void* d_ws, size_t ws_size,
                              hipStream_t stream) {
  const float* x     = (const float*)d_in[0];
  const float* normw = (const float*)d_in[1];
  const float* Wk    = (const float*)d_in[2];
  const float* Wv    = (const float*)d_in[3];
  const float* Wo    = (const float*)d_in[4];
  const float* Wb    = (const float*)d_in[5];
  const float* bb    = (const float*)d_in[6];
  const float* Wg    = (const float*)d_in[7];
  const float* bg    = (const float*)d_in[8];
  float* y = (float*)d_out;

  char* ws = (char*)d_ws;
  u16* xn    = (u16*)ws;   ws += (long)ROWS * D_ * 2;      // 33.5 MB (reused as P1^T)
  u16* Wcomb = (u16*)ws;   ws += (long)NPAD * D_ * 2;      // 4.7 MB
  u16* Wob   = (u16*)ws;   ws += (long)D_ * D_ * 2;        // 2 MB
  u16* kvb   = (u16*)ws;   ws += (long)ROWS * NPAD * 2;    // 75.5 MB (k,v -> Q,M in place)
  float* bA  = (float*)ws; ws += (long)B_ * H_ * T_ * 4;
  float* gA  = (float*)ws; ws += (long)B_ * H_ * T_ * 4;
  u16* outb  = (u16*)ws;   ws += (long)ROWS * D_ * 2;
  u16* r1b   = (u16*)ws;   ws += (long)64 * 64 * 4096 * 2; // R1^T

  const int LDSB = 3 * 32768;
  bool big = true;
  if (hipFuncSetAttribute(reinterpret_cast<const void*>(gemm256<0,0>),
        hipFuncAttributeMaxDynamicSharedMemorySize, LDSB) != hipSuccess) big = false;
  if (hipFuncSetAttribute(reinterpret_cast<const void*>(gemm256<1,1>),
        hipFuncAttributeMaxDynamicSharedMemorySize, LDSB) != hipSuccess) big = false;

  const long prep_total = (long)NPAD * D_ + (long)D_ * D_;
  prep_w<<<dim3((unsigned)(prep_total / 256)), dim3(256), 0, stream>>>(
      Wk, Wv, Wb, Wg, Wo, Wcomb, Wob);
  rmsnorm_k<<<dim3(ROWS), dim3(256), 0, stream>>>(x, normw, xn);
  if (big)
    gemm256<0, 0><<<dim3(NPAD / 256, ROWS / 256), dim3(512), LDSB, stream>>>(
        xn, Wcomb, kvb, (float*)nullptr, (const float*)nullptr, ROWS, NPAD, D_);
  else
    gemm_nt<0, 0><<<dim3(NPAD / 128, ROWS / 128), dim3(256), 0, stream>>>(
        xn, Wcomb, kvb, (float*)nullptr, (const float*)nullptr, ROWS, NPAD, D_);
  sigmoid_bg<<<dim3(ROWS * 32 / 256), dim3(256), 0, stream>>>(kvb, bb, bg, bA, gA);
  chunk1<<<dim3(4096), dim3(256), 0, stream>>>(kvb, bA, gA, xn, r1b);
  chunk2<<<dim3(256), dim3(256), 0, stream>>>(kvb, xn, r1b, outb);
  if (big)
    gemm256<1, 1><<<dim3(D_ / 256, ROWS / 256), dim3(512), LDSB, stream>>>(
        outb, Wob, (u16*)nullptr, y, x, ROWS, D_, D_);
  else
    gemm_nt<1, 1><<<dim3(D_ / 128, ROWS / 128), dim3(256), 0, stream>>>(
        outb, Wob, (u16*)nullptr, y, x, ROWS, D_, D_);
}